// Round 3
// baseline (5751.706 us; speedup 1.0000x reference)
//
#include <hip/hip_runtime.h>

typedef unsigned short u16;
typedef unsigned int   u32;

// f32 weight slab layout (offsets in floats). All 64x64 matrices stored TRANSPOSED:
// WT[c*64+k] = W[k*64+c] so per-output-channel rows are contiguous.
#define OF_WIN   0
#define OF_WLIN  4096
#define OF_WSRC  8192
#define OF_WDST  12288
#define OF_WP1   16384   // [64][4] padded (K=3)
#define OF_WP2   16640
#define OF_WA1   20736
#define OF_WA2   24832
#define OF_WOUT  28928
#define OF_BIAS  33024   // bin,bp1,bp2,ba1,ba2,bout (6 x 64)
#define WF_TOT   33408

// ---------- transpose/copy all weights+biases (f32 -> f32 slab) ----------
__global__ __launch_bounds__(256) void k_prep(
  const float* __restrict__ Win, const float* __restrict__ Wlin,
  const float* __restrict__ Wsrc, const float* __restrict__ Wdst,
  const float* __restrict__ Wp1, const float* __restrict__ Wp2,
  const float* __restrict__ Wa1, const float* __restrict__ Wa2,
  const float* __restrict__ Wout,
  const float* __restrict__ bin, const float* __restrict__ bp1, const float* __restrict__ bp2,
  const float* __restrict__ ba1, const float* __restrict__ ba2, const float* __restrict__ bout,
  float* __restrict__ Wf)
{
  int idx = blockIdx.x*256 + threadIdx.x;
  if(idx < 32768){
    int i = idx >> 12, r = idx & 4095, c = r >> 6, k = r & 63;
    const float* src; int dst;
    switch(i){
      case 0: src=Win;  dst=OF_WIN;  break;
      case 1: src=Wlin; dst=OF_WLIN; break;
      case 2: src=Wsrc; dst=OF_WSRC; break;
      case 3: src=Wdst; dst=OF_WDST; break;
      case 4: src=Wp2;  dst=OF_WP2;  break;
      case 5: src=Wa1;  dst=OF_WA1;  break;
      case 6: src=Wa2;  dst=OF_WA2;  break;
      default:src=Wout; dst=OF_WOUT; break;
    }
    Wf[dst + c*64 + k] = src[k*64 + c];
  } else if(idx < 33024){
    int j = idx - 32768, c = j >> 2, k = j & 3;
    Wf[OF_WP1 + c*4 + k] = (k<3) ? Wp1[k*64 + c] : 0.f;
  } else if(idx < 33408){
    int j = idx - 33024, which = j >> 6, c = j & 63;
    const float* b;
    switch(which){ case 0:b=bin;break; case 1:b=bp1;break; case 2:b=bp2;break;
                   case 3:b=ba1;break; case 4:b=ba2;break; default:b=bout;break; }
    Wf[OF_BIAS + j] = b[c];
  }
}

// ---------- node side: h=relu(x@Win+b); v=h@Wlin; asrc=h@Wsrc; adst=h@Wdst
__global__ __launch_bounds__(64) void k_node_s(
  const float* __restrict__ x, const float* __restrict__ Wf,
  float* __restrict__ vf, float* __restrict__ asof, float* __restrict__ adof, int N)
{
  int node = blockIdx.x*64 + threadIdx.x;
  if(node >= N) return;
  float xr[64];
  const float4* x4 = (const float4*)(x + (size_t)node*64);
#pragma unroll
  for(int q=0;q<16;q++){
    float4 u = x4[q];
    xr[q*4+0]=u.x; xr[q*4+1]=u.y; xr[q*4+2]=u.z; xr[q*4+3]=u.w;
  }
  float h[64];
  const float* binf = Wf + OF_BIAS;
#pragma unroll 2
  for(int c=0;c<64;c++){
    float a = binf[c];
    const float* wr = Wf + OF_WIN + c*64;
#pragma unroll
    for(int k=0;k<64;k++) a += xr[k]*wr[k];
    h[c] = fmaxf(a, 0.f);
  }
#pragma unroll 2
  for(int c=0;c<64;c++){
    const float* w1 = Wf + OF_WLIN + c*64;
    const float* w2 = Wf + OF_WSRC + c*64;
    const float* w3 = Wf + OF_WDST + c*64;
    float a1=0.f, a2=0.f, a3=0.f;
#pragma unroll
    for(int k=0;k<64;k++){ float hv=h[k]; a1+=hv*w1[k]; a2+=hv*w2[k]; a3+=hv*w3[k]; }
    vf  [(size_t)node*64+c]=a1;
    asof[(size_t)node*64+c]=a2;
    adof[(size_t)node*64+c]=a3;
  }
}

// ---------- edge side: delta MLP, attn MLP, w=exp(logit), atomic num/S
__global__ __launch_bounds__(64) void k_edge_s(
  const int* __restrict__ ei, const float* __restrict__ pos,
  const float* __restrict__ Wf,
  const float* __restrict__ vf, const float* __restrict__ asof, const float* __restrict__ adof,
  float* __restrict__ S, float* __restrict__ num, int E)
{
  __shared__ float dsh[64][65];   // per-thread delta[64] (thread-private, padded stride)
  int tid = threadIdx.x;
  int e = blockIdx.x*64 + tid;
  if(e >= E) return;
  int sid = ei[e], did = ei[(size_t)E + e];
  float rel0 = pos[did*3+0] - pos[sid*3+0];
  float rel1 = pos[did*3+1] - pos[sid*3+1];
  float rel2 = pos[did*3+2] - pos[sid*3+2];
  const float* bp1f = Wf + OF_BIAS + 64;
  const float* bp2f = Wf + OF_BIAS + 128;
  const float* ba1f = Wf + OF_BIAS + 192;
  const float* ba2f = Wf + OF_BIAS + 256;

  float A[64];                    // t1, later ali
#pragma unroll 4
  for(int c=0;c<64;c++){
    const float* w = Wf + OF_WP1 + c*4;
    A[c] = fmaxf(rel0*w[0] + rel1*w[1] + rel2*w[2] + bp1f[c], 0.f);
  }
#pragma unroll 2
  for(int c=0;c<64;c++){
    const float* w = Wf + OF_WP2 + c*64;
    float a = bp2f[c];
#pragma unroll
    for(int k=0;k<64;k++) a += A[k]*w[k];
    dsh[tid][c] = a;              // delta kept for aggregation
  }
  // ali = a_dst[did] - a_src[sid] + delta   (overwrite A)
  const float4* ad4 = (const float4*)(adof + (size_t)did*64);
  const float4* as4 = (const float4*)(asof + (size_t)sid*64);
#pragma unroll
  for(int c4=0;c4<16;c4++){
    float4 d = ad4[c4], s = as4[c4];
    A[c4*4+0] = d.x - s.x + dsh[tid][c4*4+0];
    A[c4*4+1] = d.y - s.y + dsh[tid][c4*4+1];
    A[c4*4+2] = d.z - s.z + dsh[tid][c4*4+2];
    A[c4*4+3] = d.w - s.w + dsh[tid][c4*4+3];
  }
  float U[64];
#pragma unroll 2
  for(int c=0;c<64;c++){
    const float* w = Wf + OF_WA1 + c*64;
    float a = ba1f[c];
#pragma unroll
    for(int k=0;k<64;k++) a += A[k]*w[k];
    U[c] = fmaxf(a, 0.f);
  }
  const float4* vv4 = (const float4*)(vf + (size_t)sid*64);
  float* nrow = num + (size_t)did*64;
  float* srow = S   + (size_t)did*64;
  for(int c4=0;c4<16;c4++){
    float4 vv = vv4[c4];
    float vvv[4] = {vv.x, vv.y, vv.z, vv.w};
#pragma unroll
    for(int m=0;m<4;m++){
      int c = c4*4+m;
      const float* w = Wf + OF_WA2 + c*64;
      float l = ba2f[c];
#pragma unroll
      for(int k=0;k<64;k++) l += U[k]*w[k];
      float wgt = __expf(fminf(l, 80.f));   // logits O(1); softmax shift cancels in num/S
      atomicAdd(&nrow[c], wgt*(vvv[m] + dsh[tid][c]));
      atomicAdd(&srow[c], wgt);
    }
  }
}

// ---------- out = relu((num/S) @ Wout + bout), f32 output
__global__ __launch_bounds__(64) void k_out_s(
  const float* __restrict__ num, const float* __restrict__ S,
  const float* __restrict__ Wf, float* __restrict__ out, int N)
{
  int node = blockIdx.x*64 + threadIdx.x;
  if(node >= N) return;
  float agg[64];
  const float4* n4 = (const float4*)(num + (size_t)node*64);
  const float4* s4 = (const float4*)(S   + (size_t)node*64);
#pragma unroll
  for(int c4=0;c4<16;c4++){
    float4 n = n4[c4], s = s4[c4];
    agg[c4*4+0] = n.x/(s.x+1e-16f);
    agg[c4*4+1] = n.y/(s.y+1e-16f);
    agg[c4*4+2] = n.z/(s.z+1e-16f);
    agg[c4*4+3] = n.w/(s.w+1e-16f);
  }
  const float* bof = Wf + OF_BIAS + 320;
#pragma unroll 2
  for(int c=0;c<64;c++){
    const float* w = Wf + OF_WOUT + c*64;
    float a = bof[c];
#pragma unroll
    for(int k=0;k<64;k++) a += agg[k]*w[k];
    out[(size_t)node*64+c] = fmaxf(a, 0.f);
  }
}

extern "C" void kernel_launch(void* const* d_in, const int* in_sizes, int n_in,
                              void* d_out, int out_size, void* d_ws, size_t ws_size,
                              hipStream_t stream){
  const float* x   =(const float*)d_in[0];
  const float* pos =(const float*)d_in[1];
  const int*   ei  =(const int*)d_in[2];
  const float* Win =(const float*)d_in[3];  const float* bin=(const float*)d_in[4];
  const float* Wlin=(const float*)d_in[5];  const float* Wsrc=(const float*)d_in[6];
  const float* Wdst=(const float*)d_in[7];
  const float* Wp1 =(const float*)d_in[8];  const float* bp1=(const float*)d_in[9];
  const float* Wp2 =(const float*)d_in[10]; const float* bp2=(const float*)d_in[11];
  const float* Wa1 =(const float*)d_in[12]; const float* ba1=(const float*)d_in[13];
  const float* Wa2 =(const float*)d_in[14]; const float* ba2=(const float*)d_in[15];
  const float* Wout=(const float*)d_in[16]; const float* bout=(const float*)d_in[17];
  int N = in_sizes[0]/64;
  int E = in_sizes[2]/2;

  float* Wf   = (float*)d_ws;                 // 33408 f32 (133,632 B)
  float* vf   = Wf + WF_TOT;                  // [N*64] f32
  float* asof = vf   + (size_t)N*64;          // [N*64] f32
  float* adof = asof + (size_t)N*64;          // [N*64] f32
  float* S    = adof + (size_t)N*64;          // [N*64] f32
  float* num  = S    + (size_t)N*64;          // [N*64] f32

  hipMemsetAsync(S, 0, (size_t)N*64*2*sizeof(float), stream);
  k_prep<<<dim3(131), dim3(256), 0, stream>>>(Win,Wlin,Wsrc,Wdst,Wp1,Wp2,Wa1,Wa2,Wout,
                                              bin,bp1,bp2,ba1,ba2,bout, Wf);
  k_node_s<<<dim3((N+63)/64), dim3(64), 0, stream>>>(x, Wf, vf, asof, adof, N);
  k_edge_s<<<dim3((E+63)/64), dim3(64), 0, stream>>>(ei, pos, Wf, vf, asof, adof, S, num, E);
  k_out_s<<<dim3((N+63)/64), dim3(64), 0, stream>>>(num, S, Wf, (float*)d_out, N);
}

// Round 4
// 805.039 us; speedup vs baseline: 7.1446x; 7.1446x over previous
//
#include <hip/hip_runtime.h>

typedef unsigned short u16;
typedef unsigned int   u32;
typedef __attribute__((ext_vector_type(8))) short bf16x8;
typedef __attribute__((ext_vector_type(4))) float f32x4;

#define DEV static __device__ __forceinline__

DEV float bf2f(u16 u){ union{u32 i; float f;} v; v.i=((u32)u)<<16; return v.f; }
DEV u16 f2bf(float f){ union{float f; u32 i;} v; v.f=f; u32 u=v.i;
                       return (u16)((u + 0x7FFFu + ((u>>16)&1u))>>16); }
DEV void ldsfence(){ asm volatile("s_waitcnt lgkmcnt(0)" ::: "memory"); }

// ---- f32 slab (transposed weights for scalar kernels) ----
#define OF_WIN   0
#define OF_WLIN  4096
#define OF_WSRC  8192
#define OF_WDST  12288
#define OF_WP1   16384   // [64][4] padded (K=3)
#define OF_WP2   16640
#define OF_WA1   20736
#define OF_WA2   24832
#define OF_WOUT  28928
#define OF_BIAS  33024   // bin,bp1,bp2,ba1,ba2,bout (6 x 64)
#define WF_TOT   33408
// ---- bf16 slab (original [K][64] layout for MFMA B-frags), offsets in u16 ----
#define UB_P1    0       // [4][64], row 3 zero
#define UB_P2    256     // [64][64]
#define UB_A1    4352
#define UB_A2    8448
#define UB_TOT   12544

// B fragment (ntile nt, kstep s): W[k][nt*16+t], k=s*32+q*8+j, from bf16 [K][64]
DEV bf16x8 load_bfrag(const u16* __restrict__ W, int nt, int s, int q, int t, int K){
  bf16x8 r;
#pragma unroll
  for(int j=0;j<8;j++){
    int k = s*32 + q*8 + j;
    r[j] = (short)((k < K) ? W[k*64 + nt*16 + t] : (u16)0);
  }
  return r;
}
DEV bf16x8 lds_read_chunk(const u32* l32, int dw){ // 8 bf16 from 4 dwords
  union{ u32 d[4]; bf16x8 v; } u;
#pragma unroll
  for(int p=0;p<4;p++) u.d[p] = l32[dw+p];
  return u.v;
}

// ---------- weight prep: f32 transposed slab + bf16 [K][64] slab ----------
__global__ __launch_bounds__(256) void k_prep(
  const float* __restrict__ Win, const float* __restrict__ Wlin,
  const float* __restrict__ Wsrc, const float* __restrict__ Wdst,
  const float* __restrict__ Wp1, const float* __restrict__ Wp2,
  const float* __restrict__ Wa1, const float* __restrict__ Wa2,
  const float* __restrict__ Wout,
  const float* __restrict__ bin, const float* __restrict__ bp1, const float* __restrict__ bp2,
  const float* __restrict__ ba1, const float* __restrict__ ba2, const float* __restrict__ bout,
  float* __restrict__ Wf, u16* __restrict__ Wb)
{
  int idx = blockIdx.x*256 + threadIdx.x;
  if(idx < 32768){
    int i = idx >> 12, r = idx & 4095, c = r >> 6, k = r & 63;
    const float* src; int dst;
    switch(i){
      case 0: src=Win;  dst=OF_WIN;  break;
      case 1: src=Wlin; dst=OF_WLIN; break;
      case 2: src=Wsrc; dst=OF_WSRC; break;
      case 3: src=Wdst; dst=OF_WDST; break;
      case 4: src=Wp2;  dst=OF_WP2;  break;
      case 5: src=Wa1;  dst=OF_WA1;  break;
      case 6: src=Wa2;  dst=OF_WA2;  break;
      default:src=Wout; dst=OF_WOUT; break;
    }
    Wf[dst + c*64 + k] = src[k*64 + c];
  } else if(idx < 33024){
    int j = idx - 32768, c = j >> 2, k = j & 3;
    Wf[OF_WP1 + c*4 + k] = (k<3) ? Wp1[k*64 + c] : 0.f;
  } else if(idx < 33408){
    int j = idx - 33024, which = j >> 6, c = j & 63;
    const float* b;
    switch(which){ case 0:b=bin;break; case 1:b=bp1;break; case 2:b=bp2;break;
                   case 3:b=ba1;break; case 4:b=ba2;break; default:b=bout;break; }
    Wf[OF_BIAS + j] = b[c];
  } else if(idx < 33408 + UB_TOT){
    int j = idx - 33408;
    if(j < 256){
      int k = j >> 6, c = j & 63;
      Wb[UB_P1 + j] = (k<3) ? f2bf(Wp1[k*64 + c]) : (u16)0;
    } else {
      int j2 = j - 256, mat = j2 >> 12, r = j2 & 4095;
      const float* src = (mat==0) ? Wp2 : (mat==1) ? Wa1 : Wa2;
      Wb[UB_P2 + mat*4096 + r] = f2bf(src[r]);
    }
  }
}

// ---------- node side (scalar f32, unchanged from validated R3) ----------
__global__ __launch_bounds__(64) void k_node_s(
  const float* __restrict__ x, const float* __restrict__ Wf,
  float* __restrict__ vf, float* __restrict__ asof, float* __restrict__ adof, int N)
{
  int node = blockIdx.x*64 + threadIdx.x;
  if(node >= N) return;
  float xr[64];
  const float4* x4 = (const float4*)(x + (size_t)node*64);
#pragma unroll
  for(int q=0;q<16;q++){
    float4 u = x4[q];
    xr[q*4+0]=u.x; xr[q*4+1]=u.y; xr[q*4+2]=u.z; xr[q*4+3]=u.w;
  }
  float h[64];
  const float* binf = Wf + OF_BIAS;
#pragma unroll 2
  for(int c=0;c<64;c++){
    float a = binf[c];
    const float* wr = Wf + OF_WIN + c*64;
#pragma unroll
    for(int k=0;k<64;k++) a += xr[k]*wr[k];
    h[c] = fmaxf(a, 0.f);
  }
#pragma unroll 2
  for(int c=0;c<64;c++){
    const float* w1 = Wf + OF_WLIN + c*64;
    const float* w2 = Wf + OF_WSRC + c*64;
    const float* w3 = Wf + OF_WDST + c*64;
    float a1=0.f, a2=0.f, a3=0.f;
#pragma unroll
    for(int k=0;k<64;k++){ float hv=h[k]; a1+=hv*w1[k]; a2+=hv*w2[k]; a3+=hv*w3[k]; }
    vf  [(size_t)node*64+c]=a1;
    asof[(size_t)node*64+c]=a2;
    adof[(size_t)node*64+c]=a3;
  }
}

// ---------- CSR build ----------
__global__ __launch_bounds__(256) void k_hist(const int* __restrict__ ei, int* __restrict__ deg, int E){
  int e = blockIdx.x*256 + threadIdx.x;
  if(e < E) atomicAdd(&deg[ei[(size_t)E + e]], 1);
}

__global__ __launch_bounds__(1024) void k_scan(const int* __restrict__ deg,
                                               int* __restrict__ row_start, int N){
  __shared__ int buf[1024];
  __shared__ int carry;
  int tid = threadIdx.x;
  if(tid==0) carry = 0;
  __syncthreads();
  for(int base=0; base<N; base+=1024){
    int i = base + tid;
    int v = (i<N) ? deg[i] : 0;
    buf[tid] = v; __syncthreads();
#pragma unroll
    for(int off=1; off<1024; off<<=1){
      int u = (tid>=off) ? buf[tid-off] : 0;
      __syncthreads();
      buf[tid] += u;
      __syncthreads();
    }
    if(i<N) row_start[i] = carry + buf[tid] - v;   // exclusive
    __syncthreads();
    if(tid==0) carry += buf[1023];
    __syncthreads();
  }
  if(tid==0) row_start[N] = carry;
}

__global__ __launch_bounds__(256) void k_scatter(const int* __restrict__ ei,
    const int* __restrict__ row_start, int* __restrict__ cursor,
    int* __restrict__ sorted_src, int E){
  int e = blockIdx.x*256 + threadIdx.x;
  if(e >= E) return;
  int d = ei[(size_t)E + e];
  int p = atomicAdd(&cursor[d], 1);
  sorted_src[row_start[d] + p] = ei[e];
}

// ---------- edge pipeline: wave per dst node, 16-edge MFMA tiles, no atomics ----------
__global__ __launch_bounds__(256,2) void k_edge_m(
  const int* __restrict__ row_start, const int* __restrict__ sorted_src,
  const float* __restrict__ pos, const float* __restrict__ Wf, const u16* __restrict__ Wb,
  const float* __restrict__ vf, const float* __restrict__ asof, const float* __restrict__ adof,
  float* __restrict__ S, float* __restrict__ num, int N)
{
  __shared__ u16   sc16[4][16*66];   // bf16 scratch (t1 / u round-trips) per wave
  __shared__ float scf [4][16*66];   // f32 scratch (delta) per wave
  int lane = threadIdx.x & 63, warp = threadIdx.x >> 6;
  int t = lane & 15, q = lane >> 4;
  int d = blockIdx.x*4 + warp;
  if(d >= N) return;
  u16* lb = sc16[warp]; u32* lb32 = (u32*)lb;
  float* lf = scf[warp];

  int rs = row_start[d], re = row_start[d+1];

  // weight fragments (wave-resident)
  bf16x8 wp1f[4], wp2f[4][2], wa1f[4][2], wa2f[4][2];
#pragma unroll
  for(int nt=0;nt<4;nt++){
    wp1f[nt] = load_bfrag(Wb+UB_P1, nt, 0, q, t, 3);
#pragma unroll
    for(int s=0;s<2;s++){
      wp2f[nt][s] = load_bfrag(Wb+UB_P2, nt, s, q, t, 64);
      wa1f[nt][s] = load_bfrag(Wb+UB_A1, nt, s, q, t, 64);
      wa2f[nt][s] = load_bfrag(Wb+UB_A2, nt, s, q, t, 64);
    }
  }
  float bp1f[4], bp2f[4], ba1f[4], ba2f[4];
#pragma unroll
  for(int nt=0;nt<4;nt++){
    bp1f[nt]=Wf[OF_BIAS+ 64+nt*16+t]; bp2f[nt]=Wf[OF_BIAS+128+nt*16+t];
    ba1f[nt]=Wf[OF_BIAS+192+nt*16+t]; ba2f[nt]=Wf[OF_BIAS+256+nt*16+t];
  }
  float pdx=pos[(size_t)d*3], pdy=pos[(size_t)d*3+1], pdz=pos[(size_t)d*3+2];
  const float4* ad4 = (const float4*)(adof + (size_t)d*64);
  const float4* as4 = (const float4*)asof;
  f32x4 zero = {0.f,0.f,0.f,0.f};
  float numP[4] = {0,0,0,0}, SP[4] = {0,0,0,0};

  for(int base=rs; base<re; base+=16){
    int e = base + t;
    int sid = sorted_src[(e<re) ? e : (re-1)];

    // --- layer P1: t1 = relu(rel @ Wp1 + bp1), rel in A-frag (K=3) ---
    bf16x8 a1;
#pragma unroll
    for(int j=0;j<8;j++) a1[j]=0;
    if(q==0){
      a1[0] = (short)f2bf(pdx - pos[(size_t)sid*3+0]);
      a1[1] = (short)f2bf(pdy - pos[(size_t)sid*3+1]);
      a1[2] = (short)f2bf(pdz - pos[(size_t)sid*3+2]);
    }
    f32x4 acc[4];
#pragma unroll
    for(int nt=0;nt<4;nt++)
      acc[nt] = __builtin_amdgcn_mfma_f32_16x16x32_bf16(a1, wp1f[nt], zero, 0,0,0);

    ldsfence();
#pragma unroll
    for(int nt=0;nt<4;nt++)
#pragma unroll
      for(int r=0;r<4;r++)
        lb[(q*4+r)*66 + nt*16 + t] = f2bf(fmaxf(acc[nt][r] + bp1f[nt], 0.f));
    ldsfence();
    bf16x8 at0 = lds_read_chunk(lb32, t*33 + q*4);
    bf16x8 at1 = lds_read_chunk(lb32, t*33 + 16 + q*4);

    // --- layer P2: delta = t1 @ Wp2 + bp2 (f32 kept) ---
#pragma unroll
    for(int nt=0;nt<4;nt++){
      acc[nt] = __builtin_amdgcn_mfma_f32_16x16x32_bf16(at0, wp2f[nt][0], zero, 0,0,0);
      acc[nt] = __builtin_amdgcn_mfma_f32_16x16x32_bf16(at1, wp2f[nt][1], acc[nt], 0,0,0);
    }
    float dval[4][4];
#pragma unroll
    for(int nt=0;nt<4;nt++)
#pragma unroll
      for(int r=0;r<4;r++) dval[nt][r] = acc[nt][r] + bp2f[nt];

    ldsfence();   // WAR vs prev chunk's delta reads
#pragma unroll
    for(int nt=0;nt<4;nt++)
#pragma unroll
      for(int r=0;r<4;r++)
        lf[(q*4+r)*66 + nt*16 + t] = dval[nt][r];
    ldsfence();

    // --- ali = a_dst[d] - a_src[sid] + delta, to A-frags ---
    bf16x8 ali[2];
#pragma unroll
    for(int s=0;s<2;s++){
      float4 d0 = ad4[s*8 + q*2], d1 = ad4[s*8 + q*2 + 1];
      float4 s0 = as4[(size_t)sid*16 + s*8 + q*2], s1 = as4[(size_t)sid*16 + s*8 + q*2 + 1];
      const float* dl = lf + t*66 + s*32 + q*8;
      ali[s][0]=(short)f2bf(d0.x - s0.x + dl[0]);
      ali[s][1]=(short)f2bf(d0.y - s0.y + dl[1]);
      ali[s][2]=(short)f2bf(d0.z - s0.z + dl[2]);
      ali[s][3]=(short)f2bf(d0.w - s0.w + dl[3]);
      ali[s][4]=(short)f2bf(d1.x - s1.x + dl[4]);
      ali[s][5]=(short)f2bf(d1.y - s1.y + dl[5]);
      ali[s][6]=(short)f2bf(d1.z - s1.z + dl[6]);
      ali[s][7]=(short)f2bf(d1.w - s1.w + dl[7]);
    }

    // --- attn layer 1: u = relu(ali @ Wa1 + ba1) ---
#pragma unroll
    for(int nt=0;nt<4;nt++){
      acc[nt] = __builtin_amdgcn_mfma_f32_16x16x32_bf16(ali[0], wa1f[nt][0], zero, 0,0,0);
      acc[nt] = __builtin_amdgcn_mfma_f32_16x16x32_bf16(ali[1], wa1f[nt][1], acc[nt], 0,0,0);
    }
    ldsfence();
#pragma unroll
    for(int nt=0;nt<4;nt++)
#pragma unroll
      for(int r=0;r<4;r++)
        lb[(q*4+r)*66 + nt*16 + t] = f2bf(fmaxf(acc[nt][r] + ba1f[nt], 0.f));
    ldsfence();
    bf16x8 au0 = lds_read_chunk(lb32, t*33 + q*4);
    bf16x8 au1 = lds_read_chunk(lb32, t*33 + 16 + q*4);

    // --- attn layer 2: logits; w = exp(logit) ---
#pragma unroll
    for(int nt=0;nt<4;nt++){
      acc[nt] = __builtin_amdgcn_mfma_f32_16x16x32_bf16(au0, wa2f[nt][0], zero, 0,0,0);
      acc[nt] = __builtin_amdgcn_mfma_f32_16x16x32_bf16(au1, wa2f[nt][1], acc[nt], 0,0,0);
    }
    float wv[4][4];
#pragma unroll
    for(int nt=0;nt<4;nt++)
#pragma unroll
      for(int r=0;r<4;r++){
        bool valid = (base + q*4 + r) < re;
        wv[nt][r] = valid ? __expf(fminf(acc[nt][r] + ba2f[nt], 80.f)) : 0.f;
      }

    // --- accumulate num/S: gather v[sid_m][c] per (m=q*4+r, c=nt*16+t) ---
#pragma unroll
    for(int r=0;r<4;r++){
      int m = q*4 + r;
      int sidm = __shfl(sid, m, 64);
#pragma unroll
      for(int nt=0;nt<4;nt++){
        float vvalue = vf[(size_t)sidm*64 + nt*16 + t];
        numP[nt] += wv[nt][r] * (vvalue + dval[nt][r]);
        SP[nt]   += wv[nt][r];
      }
    }
  }

  // reduce over q (edges span q and r); lanes differing in bits 4,5
#pragma unroll
  for(int nt=0;nt<4;nt++){
    numP[nt] += __shfl_xor(numP[nt], 16, 64);
    numP[nt] += __shfl_xor(numP[nt], 32, 64);
    SP[nt]   += __shfl_xor(SP[nt],   16, 64);
    SP[nt]   += __shfl_xor(SP[nt],   32, 64);
  }
  if(q==0){
#pragma unroll
    for(int nt=0;nt<4;nt++){
      num[(size_t)d*64 + nt*16 + t] = numP[nt];
      S  [(size_t)d*64 + nt*16 + t] = SP[nt];
    }
  }
}

// ---------- out = relu((num/S) @ Wout + bout) ----------
__global__ __launch_bounds__(64) void k_out_s(
  const float* __restrict__ num, const float* __restrict__ S,
  const float* __restrict__ Wf, float* __restrict__ out, int N)
{
  int node = blockIdx.x*64 + threadIdx.x;
  if(node >= N) return;
  float agg[64];
  const float4* n4 = (const float4*)(num + (size_t)node*64);
  const float4* s4 = (const float4*)(S   + (size_t)node*64);
#pragma unroll
  for(int c4=0;c4<16;c4++){
    float4 n = n4[c4], s = s4[c4];
    agg[c4*4+0] = n.x/(s.x+1e-16f);
    agg[c4*4+1] = n.y/(s.y+1e-16f);
    agg[c4*4+2] = n.z/(s.z+1e-16f);
    agg[c4*4+3] = n.w/(s.w+1e-16f);
  }
  const float* bof = Wf + OF_BIAS + 320;
#pragma unroll 2
  for(int c=0;c<64;c++){
    const float* w = Wf + OF_WOUT + c*64;
    float a = bof[c];
#pragma unroll
    for(int k=0;k<64;k++) a += agg[k]*w[k];
    out[(size_t)node*64+c] = fmaxf(a, 0.f);
  }
}

extern "C" void kernel_launch(void* const* d_in, const int* in_sizes, int n_in,
                              void* d_out, int out_size, void* d_ws, size_t ws_size,
                              hipStream_t stream){
  const float* x   =(const float*)d_in[0];
  const float* pos =(const float*)d_in[1];
  const int*   ei  =(const int*)d_in[2];
  const float* Win =(const float*)d_in[3];  const float* bin=(const float*)d_in[4];
  const float* Wlin=(const float*)d_in[5];  const float* Wsrc=(const float*)d_in[6];
  const float* Wdst=(const float*)d_in[7];
  const float* Wp1 =(const float*)d_in[8];  const float* bp1=(const float*)d_in[9];
  const float* Wp2 =(const float*)d_in[10]; const float* bp2=(const float*)d_in[11];
  const float* Wa1 =(const float*)d_in[12]; const float* ba1=(const float*)d_in[13];
  const float* Wa2 =(const float*)d_in[14]; const float* ba2=(const float*)d_in[15];
  const float* Wout=(const float*)d_in[16]; const float* bout=(const float*)d_in[17];
  int N = in_sizes[0]/64;
  int E = in_sizes[2]/2;

  float* Wf   = (float*)d_ws;                  // WF_TOT f32
  u16*   Wb   = (u16*)(Wf + WF_TOT);           // UB_TOT u16
  float* vf   = (float*)(Wb + UB_TOT);         // [N*64]
  float* asof = vf   + (size_t)N*64;
  float* adof = asof + (size_t)N*64;
  float* S    = adof + (size_t)N*64;
  float* num  = S    + (size_t)N*64;
  int* deg       = (int*)(num + (size_t)N*64); // [N]
  int* cursor    = deg + N;                    // [N]
  int* row_start = cursor + N;                 // [N+1]
  int* sorted    = row_start + (N+1);          // [E]

  hipMemsetAsync(deg, 0, (size_t)2*N*sizeof(int), stream);   // deg + cursor
  k_prep<<<dim3(180), dim3(256), 0, stream>>>(Win,Wlin,Wsrc,Wdst,Wp1,Wp2,Wa1,Wa2,Wout,
                                              bin,bp1,bp2,ba1,ba2,bout, Wf, Wb);
  k_node_s<<<dim3((N+63)/64), dim3(64), 0, stream>>>(x, Wf, vf, asof, adof, N);
  k_hist<<<dim3((E+255)/256), dim3(256), 0, stream>>>(ei, deg, E);
  k_scan<<<dim3(1), dim3(1024), 0, stream>>>(deg, row_start, N);
  k_scatter<<<dim3((E+255)/256), dim3(256), 0, stream>>>(ei, row_start, cursor, sorted, E);
  k_edge_m<<<dim3((N+3)/4), dim3(256), 0, stream>>>(row_start, sorted, pos, Wf, Wb,
                                                    vf, asof, adof, S, num, N);
  k_out_s<<<dim3((N+63)/64), dim3(64), 0, stream>>>(num, S, Wf, (float*)d_out, N);
}

// Round 5
// 469.981 us; speedup vs baseline: 12.2382x; 1.7129x over previous
//
#include <hip/hip_runtime.h>

typedef unsigned short u16;
typedef unsigned int   u32;
typedef __attribute__((ext_vector_type(8))) short bf16x8;
typedef __attribute__((ext_vector_type(4))) float f32x4;

#define DEV static __device__ __forceinline__

DEV u16 f2bf(float f){ union{float f; u32 i;} v; v.f=f; u32 u=v.i;
                       return (u16)((u + 0x7FFFu + ((u>>16)&1u))>>16); }
DEV void ldsfence(){ asm volatile("s_waitcnt lgkmcnt(0)" ::: "memory"); }

// ---- bias slab (f32): bin,bp1,bp2,ba1,ba2,bout ----
#define NBIAS 384
// ---- fragment buffer FB: [frag][lane][8] u16; frag ids: ----
// 0..3 Wp1[nt] (K=3) | 4..11 Wp2[nt*2+s] | 12..19 Wa1 | 20..27 Wa2
// 28..35 Win | 36..43 Wlin | 44..51 Wsrc | 52..59 Wdst | 60..67 Wout
#define FB_P1 0
#define FB_P2 4
#define FB_A1 12
#define FB_A2 20
#define FB_IN 28
#define FB_LIN 36
#define FB_SRC 44
#define FB_DST 52
#define FB_OUT 60
#define NFRAG 68

DEV bf16x8 fb_load(const u16* __restrict__ FB, int frag, int lane){
  union{ uint4 u; bf16x8 v; } w;
  w.u = *(const uint4*)(FB + ((size_t)(frag*64+lane))*8);
  return w.v;
}
DEV bf16x8 lds_read_chunk(const u32* l32, int dw){
  union{ u32 d[4]; bf16x8 v; } u;
#pragma unroll
  for(int p=0;p<4;p++) u.d[p] = l32[dw+p];
  return u.v;
}

// ---------- prep: bias slab + per-lane fragment buffer ----------
__global__ __launch_bounds__(256) void k_prep(
  const float* __restrict__ Win, const float* __restrict__ Wlin,
  const float* __restrict__ Wsrc, const float* __restrict__ Wdst,
  const float* __restrict__ Wp1, const float* __restrict__ Wp2,
  const float* __restrict__ Wa1, const float* __restrict__ Wa2,
  const float* __restrict__ Wout,
  const float* __restrict__ bin, const float* __restrict__ bp1, const float* __restrict__ bp2,
  const float* __restrict__ ba1, const float* __restrict__ ba2, const float* __restrict__ bout,
  float* __restrict__ Bf, u16* __restrict__ FB)
{
  int idx = blockIdx.x*256 + threadIdx.x;
  if(idx < NBIAS){
    int which = idx >> 6, c = idx & 63;
    const float* b;
    switch(which){ case 0:b=bin;break; case 1:b=bp1;break; case 2:b=bp2;break;
                   case 3:b=ba1;break; case 4:b=ba2;break; default:b=bout;break; }
    Bf[idx] = b[c];
  } else if(idx < NBIAS + NFRAG*64){
    int j = idx - NBIAS;
    int frag = j >> 6, lane = j & 63;
    int t = lane & 15, q = lane >> 4;
    const float* src; int K = 64, nt, s;
    if(frag < 4){ src = Wp1; K = 3; nt = frag; s = 0; }
    else if(frag < 12){ int g=frag-4;  src=Wp2;  nt=g>>1; s=g&1; }
    else if(frag < 20){ int g=frag-12; src=Wa1;  nt=g>>1; s=g&1; }
    else if(frag < 28){ int g=frag-20; src=Wa2;  nt=g>>1; s=g&1; }
    else if(frag < 36){ int g=frag-28; src=Win;  nt=g>>1; s=g&1; }
    else if(frag < 44){ int g=frag-36; src=Wlin; nt=g>>1; s=g&1; }
    else if(frag < 52){ int g=frag-44; src=Wsrc; nt=g>>1; s=g&1; }
    else if(frag < 60){ int g=frag-52; src=Wdst; nt=g>>1; s=g&1; }
    else              { int g=frag-60; src=Wout; nt=g>>1; s=g&1; }
    u16* dst = FB + ((size_t)(frag*64+lane))*8;
#pragma unroll
    for(int jj=0;jj<8;jj++){
      int k = s*32 + q*8 + jj;
      dst[jj] = (k<K) ? f2bf(src[k*64 + nt*16 + t]) : (u16)0;
    }
  }
}

// ---------- node side, MFMA: h=relu(x@Win+b); v/asrc/adst = h@{Wlin,Wsrc,Wdst} ----------
__global__ __launch_bounds__(256) void k_node_m(
  const float* __restrict__ x, const float* __restrict__ Bf, const u16* __restrict__ FB,
  float* __restrict__ vf, float* __restrict__ asof, float* __restrict__ adof,
  int N, int ntiles)
{
  __shared__ u16 sc16[4][16*66];
  int lane = threadIdx.x & 63, warp = threadIdx.x >> 6;
  int t = lane & 15, q = lane >> 4;
  int tile = blockIdx.x*4 + warp;
  if(tile >= ntiles) return;
  u16* lb = sc16[warp]; u32* lb32 = (u32*)lb;
  int r0 = tile*16;
  int row = r0 + t; if(row >= N) row = N-1;

  // A-frags of x (f32 -> bf16 direct)
  const float4* x4 = (const float4*)(x + (size_t)row*64);
  bf16x8 xa[2];
#pragma unroll
  for(int s=0;s<2;s++){
    float4 u0 = x4[s*8 + q*2], u1 = x4[s*8 + q*2 + 1];
    xa[s][0]=(short)f2bf(u0.x); xa[s][1]=(short)f2bf(u0.y);
    xa[s][2]=(short)f2bf(u0.z); xa[s][3]=(short)f2bf(u0.w);
    xa[s][4]=(short)f2bf(u1.x); xa[s][5]=(short)f2bf(u1.y);
    xa[s][6]=(short)f2bf(u1.z); xa[s][7]=(short)f2bf(u1.w);
  }
  f32x4 zero = {0.f,0.f,0.f,0.f};
  f32x4 acc[4];
#pragma unroll
  for(int nt=0;nt<4;nt++){
    acc[nt] = __builtin_amdgcn_mfma_f32_16x16x32_bf16(xa[0], fb_load(FB, FB_IN+nt*2+0, lane), zero, 0,0,0);
    acc[nt] = __builtin_amdgcn_mfma_f32_16x16x32_bf16(xa[1], fb_load(FB, FB_IN+nt*2+1, lane), acc[nt], 0,0,0);
  }
  // h -> LDS -> A-frags (validated round-trip)
#pragma unroll
  for(int nt=0;nt<4;nt++)
#pragma unroll
    for(int r=0;r<4;r++)
      lb[(q*4+r)*66 + nt*16 + t] = f2bf(fmaxf(acc[nt][r] + Bf[nt*16+t], 0.f));
  ldsfence();
  bf16x8 h0 = lds_read_chunk(lb32, t*33 + q*4);
  bf16x8 h1 = lds_read_chunk(lb32, t*33 + 16 + q*4);

  const int fb0[3] = {FB_LIN, FB_SRC, FB_DST};
  float* Os[3] = {vf, asof, adof};
#pragma unroll
  for(int mtx=0; mtx<3; mtx++){
    float* O = Os[mtx];
#pragma unroll
    for(int nt=0;nt<4;nt++){
      f32x4 a = __builtin_amdgcn_mfma_f32_16x16x32_bf16(h0, fb_load(FB, fb0[mtx]+nt*2+0, lane), zero, 0,0,0);
      a = __builtin_amdgcn_mfma_f32_16x16x32_bf16(h1, fb_load(FB, fb0[mtx]+nt*2+1, lane), a, 0,0,0);
#pragma unroll
      for(int r=0;r<4;r++){
        int rr = r0 + q*4 + r;
        if(rr < N) O[(size_t)rr*64 + nt*16 + t] = a[r];
      }
    }
  }
}

// ---------- CSR build ----------
__global__ __launch_bounds__(256) void k_hist(const int* __restrict__ ei, int* __restrict__ deg, int E){
  int e = blockIdx.x*256 + threadIdx.x;
  if(e < E) atomicAdd(&deg[ei[(size_t)E + e]], 1);
}

__global__ __launch_bounds__(1024) void k_scan(const int* __restrict__ deg,
                                               int* __restrict__ row_start, int N){
  __shared__ int buf[1024];
  int tid = threadIdx.x;
  int M = (N + 1023) >> 10;
  int lo = tid*M, hi = lo+M; if(hi>N) hi=N; if(lo>N) lo=N;
  int s = 0;
  for(int j=lo;j<hi;j++) s += deg[j];
  buf[tid] = s; __syncthreads();
#pragma unroll
  for(int off=1; off<1024; off<<=1){
    int u = (tid>=off) ? buf[tid-off] : 0;
    __syncthreads();
    buf[tid] += u;
    __syncthreads();
  }
  int b = buf[tid] - s;     // exclusive
  for(int j=lo;j<hi;j++){ row_start[j] = b; b += deg[j]; }
  if(tid==1023) row_start[N] = buf[1023];
}

__global__ __launch_bounds__(256) void k_scatter(const int* __restrict__ ei,
    const int* __restrict__ row_start, int* __restrict__ cursor,
    int* __restrict__ sorted_src, int E){
  int e = blockIdx.x*256 + threadIdx.x;
  if(e >= E) return;
  int d = ei[(size_t)E + e];
  int p = atomicAdd(&cursor[d], 1);
  sorted_src[row_start[d] + p] = ei[e];
}

// ---------- edge pipeline: wave per dst node, 16-edge MFMA tiles, no atomics ----------
__global__ __launch_bounds__(256,2) void k_edge_m(
  const int* __restrict__ row_start, const int* __restrict__ sorted_src,
  const float* __restrict__ pos, const float* __restrict__ Bf, const u16* __restrict__ FB,
  const float* __restrict__ vf, const float* __restrict__ asof, const float* __restrict__ adof,
  float* __restrict__ S, float* __restrict__ num, int N)
{
  __shared__ u16   sc16[4][16*66];
  __shared__ float scf [4][16*66];
  int lane = threadIdx.x & 63, warp = threadIdx.x >> 6;
  int t = lane & 15, q = lane >> 4;
  int d = blockIdx.x*4 + warp;
  if(d >= N) return;
  u16* lb = sc16[warp]; u32* lb32 = (u32*)lb;
  float* lf = scf[warp];

  int rs = row_start[d], re = row_start[d+1];

  // wave-resident weight fragments: one uint4 load each
  bf16x8 wp1f[4], wp2f[4][2], wa1f[4][2], wa2f[4][2];
#pragma unroll
  for(int nt=0;nt<4;nt++){
    wp1f[nt] = fb_load(FB, FB_P1+nt, lane);
#pragma unroll
    for(int s=0;s<2;s++){
      wp2f[nt][s] = fb_load(FB, FB_P2+nt*2+s, lane);
      wa1f[nt][s] = fb_load(FB, FB_A1+nt*2+s, lane);
      wa2f[nt][s] = fb_load(FB, FB_A2+nt*2+s, lane);
    }
  }
  float bp1f[4], bp2f[4], ba1f[4], ba2f[4];
#pragma unroll
  for(int nt=0;nt<4;nt++){
    bp1f[nt]=Bf[ 64+nt*16+t]; bp2f[nt]=Bf[128+nt*16+t];
    ba1f[nt]=Bf[192+nt*16+t]; ba2f[nt]=Bf[256+nt*16+t];
  }
  float pdx=pos[(size_t)d*3], pdy=pos[(size_t)d*3+1], pdz=pos[(size_t)d*3+2];
  const float4* ad4 = (const float4*)(adof + (size_t)d*64);
  const float4* as4 = (const float4*)asof;
  f32x4 zero = {0.f,0.f,0.f,0.f};
  float numP[4] = {0,0,0,0}, SP[4] = {0,0,0,0};

  for(int base=rs; base<re; base+=16){
    int e = base + t;
    int sid = sorted_src[(e<re) ? e : (re-1)];

    // --- P1: t1 = relu(rel @ Wp1 + bp1) ---
    bf16x8 a1;
#pragma unroll
    for(int j=0;j<8;j++) a1[j]=0;
    if(q==0){
      a1[0] = (short)f2bf(pdx - pos[(size_t)sid*3+0]);
      a1[1] = (short)f2bf(pdy - pos[(size_t)sid*3+1]);
      a1[2] = (short)f2bf(pdz - pos[(size_t)sid*3+2]);
    }
    f32x4 acc[4];
#pragma unroll
    for(int nt=0;nt<4;nt++)
      acc[nt] = __builtin_amdgcn_mfma_f32_16x16x32_bf16(a1, wp1f[nt], zero, 0,0,0);

    ldsfence();
#pragma unroll
    for(int nt=0;nt<4;nt++)
#pragma unroll
      for(int r=0;r<4;r++)
        lb[(q*4+r)*66 + nt*16 + t] = f2bf(fmaxf(acc[nt][r] + bp1f[nt], 0.f));
    ldsfence();
    bf16x8 at0 = lds_read_chunk(lb32, t*33 + q*4);
    bf16x8 at1 = lds_read_chunk(lb32, t*33 + 16 + q*4);

    // --- P2: delta = t1 @ Wp2 + bp2 (f32) ---
#pragma unroll
    for(int nt=0;nt<4;nt++){
      acc[nt] = __builtin_amdgcn_mfma_f32_16x16x32_bf16(at0, wp2f[nt][0], zero, 0,0,0);
      acc[nt] = __builtin_amdgcn_mfma_f32_16x16x32_bf16(at1, wp2f[nt][1], acc[nt], 0,0,0);
    }
    float dval[4][4];
#pragma unroll
    for(int nt=0;nt<4;nt++)
#pragma unroll
      for(int r=0;r<4;r++) dval[nt][r] = acc[nt][r] + bp2f[nt];

    ldsfence();
#pragma unroll
    for(int nt=0;nt<4;nt++)
#pragma unroll
      for(int r=0;r<4;r++)
        lf[(q*4+r)*66 + nt*16 + t] = dval[nt][r];
    ldsfence();

    // --- ali = a_dst[d] - a_src[sid] + delta ---
    bf16x8 ali[2];
#pragma unroll
    for(int s=0;s<2;s++){
      float4 d0 = ad4[s*8 + q*2], d1 = ad4[s*8 + q*2 + 1];
      float4 s0 = as4[(size_t)sid*16 + s*8 + q*2], s1 = as4[(size_t)sid*16 + s*8 + q*2 + 1];
      const float* dl = lf + t*66 + s*32 + q*8;
      ali[s][0]=(short)f2bf(d0.x - s0.x + dl[0]);
      ali[s][1]=(short)f2bf(d0.y - s0.y + dl[1]);
      ali[s][2]=(short)f2bf(d0.z - s0.z + dl[2]);
      ali[s][3]=(short)f2bf(d0.w - s0.w + dl[3]);
      ali[s][4]=(short)f2bf(d1.x - s1.x + dl[4]);
      ali[s][5]=(short)f2bf(d1.y - s1.y + dl[5]);
      ali[s][6]=(short)f2bf(d1.z - s1.z + dl[6]);
      ali[s][7]=(short)f2bf(d1.w - s1.w + dl[7]);
    }

    // --- attn L1 ---
#pragma unroll
    for(int nt=0;nt<4;nt++){
      acc[nt] = __builtin_amdgcn_mfma_f32_16x16x32_bf16(ali[0], wa1f[nt][0], zero, 0,0,0);
      acc[nt] = __builtin_amdgcn_mfma_f32_16x16x32_bf16(ali[1], wa1f[nt][1], acc[nt], 0,0,0);
    }
    ldsfence();
#pragma unroll
    for(int nt=0;nt<4;nt++)
#pragma unroll
      for(int r=0;r<4;r++)
        lb[(q*4+r)*66 + nt*16 + t] = f2bf(fmaxf(acc[nt][r] + ba1f[nt], 0.f));
    ldsfence();
    bf16x8 au0 = lds_read_chunk(lb32, t*33 + q*4);
    bf16x8 au1 = lds_read_chunk(lb32, t*33 + 16 + q*4);

    // --- attn L2 -> logits -> w=exp ---
#pragma unroll
    for(int nt=0;nt<4;nt++){
      acc[nt] = __builtin_amdgcn_mfma_f32_16x16x32_bf16(au0, wa2f[nt][0], zero, 0,0,0);
      acc[nt] = __builtin_amdgcn_mfma_f32_16x16x32_bf16(au1, wa2f[nt][1], acc[nt], 0,0,0);
    }
    float wv[4][4];
#pragma unroll
    for(int nt=0;nt<4;nt++)
#pragma unroll
      for(int r=0;r<4;r++){
        bool valid = (base + q*4 + r) < re;
        wv[nt][r] = valid ? __expf(fminf(acc[nt][r] + ba2f[nt], 80.f)) : 0.f;
      }

    // --- accumulate ---
#pragma unroll
    for(int r=0;r<4;r++){
      int m = q*4 + r;
      int sidm = __shfl(sid, m, 64);
#pragma unroll
      for(int nt=0;nt<4;nt++){
        float vvalue = vf[(size_t)sidm*64 + nt*16 + t];
        numP[nt] += wv[nt][r] * (vvalue + dval[nt][r]);
        SP[nt]   += wv[nt][r];
      }
    }
  }

#pragma unroll
  for(int nt=0;nt<4;nt++){
    numP[nt] += __shfl_xor(numP[nt], 16, 64);
    numP[nt] += __shfl_xor(numP[nt], 32, 64);
    SP[nt]   += __shfl_xor(SP[nt],   16, 64);
    SP[nt]   += __shfl_xor(SP[nt],   32, 64);
  }
  if(q==0){
#pragma unroll
    for(int nt=0;nt<4;nt++){
      num[(size_t)d*64 + nt*16 + t] = numP[nt];
      S  [(size_t)d*64 + nt*16 + t] = SP[nt];
    }
  }
}

// ---------- out = relu((num/S) @ Wout + bout), MFMA ----------
__global__ __launch_bounds__(256) void k_out_m(
  const float* __restrict__ num, const float* __restrict__ S,
  const float* __restrict__ Bf, const u16* __restrict__ FB,
  float* __restrict__ out, int N, int ntiles)
{
  int lane = threadIdx.x & 63, warp = threadIdx.x >> 6;
  int t = lane & 15, q = lane >> 4;
  int tile = blockIdx.x*4 + warp;
  if(tile >= ntiles) return;
  int r0 = tile*16;
  int row = r0 + t; if(row >= N) row = N-1;
  const float4* n4 = (const float4*)(num + (size_t)row*64);
  const float4* s4 = (const float4*)(S   + (size_t)row*64);
  bf16x8 af[2];
#pragma unroll
  for(int s=0;s<2;s++){
    float4 n0 = n4[s*8 + q*2], n1 = n4[s*8 + q*2 + 1];
    float4 s0 = s4[s*8 + q*2], s1 = s4[s*8 + q*2 + 1];
    af[s][0]=(short)f2bf(n0.x/(s0.x+1e-16f)); af[s][1]=(short)f2bf(n0.y/(s0.y+1e-16f));
    af[s][2]=(short)f2bf(n0.z/(s0.z+1e-16f)); af[s][3]=(short)f2bf(n0.w/(s0.w+1e-16f));
    af[s][4]=(short)f2bf(n1.x/(s1.x+1e-16f)); af[s][5]=(short)f2bf(n1.y/(s1.y+1e-16f));
    af[s][6]=(short)f2bf(n1.z/(s1.z+1e-16f)); af[s][7]=(short)f2bf(n1.w/(s1.w+1e-16f));
  }
  f32x4 zero = {0.f,0.f,0.f,0.f};
#pragma unroll
  for(int nt=0;nt<4;nt++){
    f32x4 a = __builtin_amdgcn_mfma_f32_16x16x32_bf16(af[0], fb_load(FB, FB_OUT+nt*2+0, lane), zero, 0,0,0);
    a = __builtin_amdgcn_mfma_f32_16x16x32_bf16(af[1], fb_load(FB, FB_OUT+nt*2+1, lane), a, 0,0,0);
    float b = Bf[320 + nt*16 + t];
#pragma unroll
    for(int r=0;r<4;r++){
      int rr = r0 + q*4 + r;
      if(rr < N) out[(size_t)rr*64 + nt*16 + t] = fmaxf(a[r] + b, 0.f);
    }
  }
}

extern "C" void kernel_launch(void* const* d_in, const int* in_sizes, int n_in,
                              void* d_out, int out_size, void* d_ws, size_t ws_size,
                              hipStream_t stream){
  const float* x   =(const float*)d_in[0];
  const float* pos =(const float*)d_in[1];
  const int*   ei  =(const int*)d_in[2];
  const float* Win =(const float*)d_in[3];  const float* bin=(const float*)d_in[4];
  const float* Wlin=(const float*)d_in[5];  const float* Wsrc=(const float*)d_in[6];
  const float* Wdst=(const float*)d_in[7];
  const float* Wp1 =(const float*)d_in[8];  const float* bp1=(const float*)d_in[9];
  const float* Wp2 =(const float*)d_in[10]; const float* bp2=(const float*)d_in[11];
  const float* Wa1 =(const float*)d_in[12]; const float* ba1=(const float*)d_in[13];
  const float* Wa2 =(const float*)d_in[14]; const float* ba2=(const float*)d_in[15];
  const float* Wout=(const float*)d_in[16]; const float* bout=(const float*)d_in[17];
  int N = in_sizes[0]/64;
  int E = in_sizes[2]/2;

  float* Bf   = (float*)d_ws;                       // 384 f32
  u16*   FB   = (u16*)(Bf + NBIAS);                 // NFRAG*64*8 u16
  float* vf   = (float*)(FB + (size_t)NFRAG*64*8);  // [N*64]
  float* asof = vf   + (size_t)N*64;
  float* adof = asof + (size_t)N*64;
  float* S    = adof + (size_t)N*64;
  float* num  = S    + (size_t)N*64;
  int* deg       = (int*)(num + (size_t)N*64);      // [N]
  int* cursor    = deg + N;                         // [N]
  int* row_start = cursor + N;                      // [N+1]
  int* sorted    = row_start + (N+1);               // [E]

  int ntiles = (N+15)/16;
  hipMemsetAsync(deg, 0, (size_t)2*N*sizeof(int), stream);   // deg + cursor
  k_prep<<<dim3(19), dim3(256), 0, stream>>>(Win,Wlin,Wsrc,Wdst,Wp1,Wp2,Wa1,Wa2,Wout,
                                             bin,bp1,bp2,ba1,ba2,bout, Bf, FB);
  k_node_m<<<dim3((ntiles+3)/4), dim3(256), 0, stream>>>(x, Bf, FB, vf, asof, adof, N, ntiles);
  k_hist<<<dim3((E+255)/256), dim3(256), 0, stream>>>(ei, deg, E);
  k_scan<<<dim3(1), dim3(1024), 0, stream>>>(deg, row_start, N);
  k_scatter<<<dim3((E+255)/256), dim3(256), 0, stream>>>(ei, row_start, cursor, sorted, E);
  k_edge_m<<<dim3((N+3)/4), dim3(256), 0, stream>>>(row_start, sorted, pos, Bf, FB,
                                                    vf, asof, adof, S, num, N);
  k_out_m<<<dim3((ntiles+3)/4), dim3(256), 0, stream>>>(num, S, Bf, FB, (float*)d_out, N, ntiles);
}

// Round 6
// 453.391 us; speedup vs baseline: 12.6860x; 1.0366x over previous
//
#include <hip/hip_runtime.h>

typedef unsigned short u16;
typedef unsigned int   u32;
typedef unsigned long long u64;
typedef __attribute__((ext_vector_type(8))) short bf16x8;
typedef __attribute__((ext_vector_type(4))) float f32x4;

#define DEV static __device__ __forceinline__

DEV u16 f2bf(float f){ union{float f; u32 i;} v; v.f=f; u32 u=v.i;
                       return (u16)((u + 0x7FFFu + ((u>>16)&1u))>>16); }
DEV void ldsfence(){ asm volatile("s_waitcnt lgkmcnt(0)" ::: "memory"); }

// ---- bias slab (f32): bin,bp1,bp2,ba1,ba2,bout ----
#define NBIAS 384
// ---- fragment buffer FB: [frag][lane][8] u16 ----
#define FB_P1 0
#define FB_P2 4
#define FB_A1 12
#define FB_A2 20
#define FB_IN 28
#define FB_LIN 36
#define FB_SRC 44
#define FB_DST 52
#define FB_OUT 60
#define NFRAG 68

DEV bf16x8 fb_load(const u16* __restrict__ FB, int frag, int lane){
  union{ uint4 u; bf16x8 v; } w;
  w.u = *(const uint4*)(FB + ((size_t)(frag*64+lane))*8);
  return w.v;
}
DEV bf16x8 lds_read_chunk(const u32* l32, int dw){
  union{ u32 d[4]; bf16x8 v; } u;
#pragma unroll
  for(int p=0;p<4;p++) u.d[p] = l32[dw+p];
  return u.v;
}

// ---------- prep: bias slab + per-lane fragment buffer ----------
__global__ __launch_bounds__(256) void k_prep(
  const float* __restrict__ Win, const float* __restrict__ Wlin,
  const float* __restrict__ Wsrc, const float* __restrict__ Wdst,
  const float* __restrict__ Wp1, const float* __restrict__ Wp2,
  const float* __restrict__ Wa1, const float* __restrict__ Wa2,
  const float* __restrict__ Wout,
  const float* __restrict__ bin, const float* __restrict__ bp1, const float* __restrict__ bp2,
  const float* __restrict__ ba1, const float* __restrict__ ba2, const float* __restrict__ bout,
  float* __restrict__ Bf, u16* __restrict__ FB)
{
  int idx = blockIdx.x*256 + threadIdx.x;
  if(idx < NBIAS){
    int which = idx >> 6, c = idx & 63;
    const float* b;
    switch(which){ case 0:b=bin;break; case 1:b=bp1;break; case 2:b=bp2;break;
                   case 3:b=ba1;break; case 4:b=ba2;break; default:b=bout;break; }
    Bf[idx] = b[c];
  } else if(idx < NBIAS + NFRAG*64){
    int j = idx - NBIAS;
    int frag = j >> 6, lane = j & 63;
    int t = lane & 15, q = lane >> 4;
    const float* src; int K = 64, nt, s;
    if(frag < 4){ src = Wp1; K = 3; nt = frag; s = 0; }
    else if(frag < 12){ int g=frag-4;  src=Wp2;  nt=g>>1; s=g&1; }
    else if(frag < 20){ int g=frag-12; src=Wa1;  nt=g>>1; s=g&1; }
    else if(frag < 28){ int g=frag-20; src=Wa2;  nt=g>>1; s=g&1; }
    else if(frag < 36){ int g=frag-28; src=Win;  nt=g>>1; s=g&1; }
    else if(frag < 44){ int g=frag-36; src=Wlin; nt=g>>1; s=g&1; }
    else if(frag < 52){ int g=frag-44; src=Wsrc; nt=g>>1; s=g&1; }
    else if(frag < 60){ int g=frag-52; src=Wdst; nt=g>>1; s=g&1; }
    else              { int g=frag-60; src=Wout; nt=g>>1; s=g&1; }
    u16* dst = FB + ((size_t)(frag*64+lane))*8;
#pragma unroll
    for(int jj=0;jj<8;jj++){
      int k = s*32 + q*8 + jj;
      dst[jj] = (k<K) ? f2bf(src[k*64 + nt*16 + t]) : (u16)0;
    }
  }
}

// ---------- node side, MFMA (validated R5) ----------
__global__ __launch_bounds__(256) void k_node_m(
  const float* __restrict__ x, const float* __restrict__ Bf, const u16* __restrict__ FB,
  float* __restrict__ vf, float* __restrict__ asof, float* __restrict__ adof,
  int N, int ntiles)
{
  __shared__ u16 sc16[4][16*66];
  int lane = threadIdx.x & 63, warp = threadIdx.x >> 6;
  int t = lane & 15, q = lane >> 4;
  int tile = blockIdx.x*4 + warp;
  if(tile >= ntiles) return;
  u16* lb = sc16[warp]; u32* lb32 = (u32*)lb;
  int r0 = tile*16;
  int row = r0 + t; if(row >= N) row = N-1;

  const float4* x4 = (const float4*)(x + (size_t)row*64);
  bf16x8 xa[2];
#pragma unroll
  for(int s=0;s<2;s++){
    float4 u0 = x4[s*8 + q*2], u1 = x4[s*8 + q*2 + 1];
    xa[s][0]=(short)f2bf(u0.x); xa[s][1]=(short)f2bf(u0.y);
    xa[s][2]=(short)f2bf(u0.z); xa[s][3]=(short)f2bf(u0.w);
    xa[s][4]=(short)f2bf(u1.x); xa[s][5]=(short)f2bf(u1.y);
    xa[s][6]=(short)f2bf(u1.z); xa[s][7]=(short)f2bf(u1.w);
  }
  f32x4 zero = {0.f,0.f,0.f,0.f};
  f32x4 acc[4];
#pragma unroll
  for(int nt=0;nt<4;nt++){
    acc[nt] = __builtin_amdgcn_mfma_f32_16x16x32_bf16(xa[0], fb_load(FB, FB_IN+nt*2+0, lane), zero, 0,0,0);
    acc[nt] = __builtin_amdgcn_mfma_f32_16x16x32_bf16(xa[1], fb_load(FB, FB_IN+nt*2+1, lane), acc[nt], 0,0,0);
  }
#pragma unroll
  for(int nt=0;nt<4;nt++)
#pragma unroll
    for(int r=0;r<4;r++)
      lb[(q*4+r)*66 + nt*16 + t] = f2bf(fmaxf(acc[nt][r] + Bf[nt*16+t], 0.f));
  ldsfence();
  bf16x8 h0 = lds_read_chunk(lb32, t*33 + q*4);
  bf16x8 h1 = lds_read_chunk(lb32, t*33 + 16 + q*4);

  const int fb0[3] = {FB_LIN, FB_SRC, FB_DST};
  float* Os[3] = {vf, asof, adof};
#pragma unroll
  for(int mtx=0; mtx<3; mtx++){
    float* O = Os[mtx];
#pragma unroll
    for(int nt=0;nt<4;nt++){
      f32x4 a = __builtin_amdgcn_mfma_f32_16x16x32_bf16(h0, fb_load(FB, fb0[mtx]+nt*2+0, lane), zero, 0,0,0);
      a = __builtin_amdgcn_mfma_f32_16x16x32_bf16(h1, fb_load(FB, fb0[mtx]+nt*2+1, lane), a, 0,0,0);
#pragma unroll
      for(int r=0;r<4;r++){
        int rr = r0 + q*4 + r;
        if(rr < N) O[(size_t)rr*64 + nt*16 + t] = a[r];
      }
    }
  }
}

// ---------- CSR build ----------
__global__ __launch_bounds__(256) void k_hist(const int* __restrict__ ei, int* __restrict__ deg, int E){
  int e = blockIdx.x*256 + threadIdx.x;
  if(e < E) atomicAdd(&deg[ei[(size_t)E + e]], 1);
}

__global__ __launch_bounds__(1024) void k_scan(const int* __restrict__ deg,
                                               int* __restrict__ row_start, int N){
  __shared__ int buf[1024];
  int tid = threadIdx.x;
  int M = (N + 1023) >> 10;
  int lo = tid*M, hi = lo+M; if(hi>N) hi=N; if(lo>N) lo=N;
  int s = 0;
  for(int j=lo;j<hi;j++) s += deg[j];
  buf[tid] = s; __syncthreads();
#pragma unroll
  for(int off=1; off<1024; off<<=1){
    int u = (tid>=off) ? buf[tid-off] : 0;
    __syncthreads();
    buf[tid] += u;
    __syncthreads();
  }
  int b = buf[tid] - s;
  for(int j=lo;j<hi;j++){ row_start[j] = b; b += deg[j]; }
  if(tid==1023) row_start[N] = buf[1023];
}

__global__ __launch_bounds__(256) void k_scatter(const int* __restrict__ ei,
    const int* __restrict__ row_start, int* __restrict__ cursor,
    int* __restrict__ sorted_src, int* __restrict__ sorted_dst, int E){
  int e = blockIdx.x*256 + threadIdx.x;
  if(e >= E) return;
  int d = ei[(size_t)E + e];
  int p = atomicAdd(&cursor[d], 1);
  int pos = row_start[d] + p;
  sorted_src[pos] = ei[e];
  sorted_dst[pos] = d;
}

// ---------- segment flush: reduce over q, store (interior) or atomic (boundary) ----------
DEV void flushseg(int d, float* numP, float* SP, const int* __restrict__ row_start,
                  float* __restrict__ num, float* __restrict__ S,
                  int lo, int hi, int q, int t){
  if(d < 0) return;
#pragma unroll
  for(int nt=0;nt<4;nt++){
    numP[nt] += __shfl_xor(numP[nt], 16, 64);
    numP[nt] += __shfl_xor(numP[nt], 32, 64);
    SP[nt]   += __shfl_xor(SP[nt],   16, 64);
    SP[nt]   += __shfl_xor(SP[nt],   32, 64);
  }
  bool partial = (row_start[d] < lo) || (row_start[d+1] > hi);
  if(q==0){
#pragma unroll
    for(int nt=0;nt<4;nt++){
      size_t off = (size_t)d*64 + nt*16 + t;
      if(partial){ atomicAdd(&num[off], numP[nt]); atomicAdd(&S[off], SP[nt]); }
      else       { num[off] = numP[nt]; S[off] = SP[nt]; }
    }
  }
#pragma unroll
  for(int nt=0;nt<4;nt++){ numP[nt]=0.f; SP[nt]=0.f; }
}

// ---------- packed edge pipeline: wave owns contiguous tile range ----------
__global__ __launch_bounds__(256,2) void k_edge_p(
  const int* __restrict__ row_start,
  const int* __restrict__ sorted_src, const int* __restrict__ sorted_dst,
  const float* __restrict__ pos, const float* __restrict__ Bf, const u16* __restrict__ FB,
  const float* __restrict__ vf, const float* __restrict__ asof, const float* __restrict__ adof,
  float* __restrict__ S, float* __restrict__ num, int E, int ntile, int tpw)
{
  __shared__ u16   sc16[4][16*66];
  __shared__ float scf [4][16*66];
  int lane = threadIdx.x & 63, warp = threadIdx.x >> 6;
  int t = lane & 15, q = lane >> 4;
  int wid = blockIdx.x*4 + warp;
  int tile0 = wid*tpw, tile1 = tile0 + tpw;
  if(tile0 >= ntile) return;
  if(tile1 > ntile) tile1 = ntile;
  int lo = tile0*16, hi = tile1*16; if(hi > E) hi = E;
  u16* lb = sc16[warp]; u32* lb32 = (u32*)lb;
  float* lf = scf[warp];

  bf16x8 wp1f[4], wp2f[4][2], wa1f[4][2], wa2f[4][2];
#pragma unroll
  for(int nt=0;nt<4;nt++){
    wp1f[nt] = fb_load(FB, FB_P1+nt, lane);
#pragma unroll
    for(int s=0;s<2;s++){
      wp2f[nt][s] = fb_load(FB, FB_P2+nt*2+s, lane);
      wa1f[nt][s] = fb_load(FB, FB_A1+nt*2+s, lane);
      wa2f[nt][s] = fb_load(FB, FB_A2+nt*2+s, lane);
    }
  }
  float bp1f[4], bp2f[4], ba1f[4], ba2f[4];
#pragma unroll
  for(int nt=0;nt<4;nt++){
    bp1f[nt]=Bf[ 64+nt*16+t]; bp2f[nt]=Bf[128+nt*16+t];
    ba1f[nt]=Bf[192+nt*16+t]; ba2f[nt]=Bf[256+nt*16+t];
  }
  const float4* as4 = (const float4*)asof;
  const float4* ad4a = (const float4*)adof;
  f32x4 zero = {0.f,0.f,0.f,0.f};
  float numP[4] = {0,0,0,0}, SP[4] = {0,0,0,0};
  int cur_d = -1;

  for(int tb = lo; tb < hi; tb += 16){
    int e = tb + t; int ec = (e < hi) ? e : (hi-1);
    int sid = sorted_src[ec];
    int did = sorted_dst[ec];

    // --- P1 ---
    bf16x8 a1;
#pragma unroll
    for(int j=0;j<8;j++) a1[j]=0;
    if(q==0){
      a1[0] = (short)f2bf(pos[(size_t)did*3+0] - pos[(size_t)sid*3+0]);
      a1[1] = (short)f2bf(pos[(size_t)did*3+1] - pos[(size_t)sid*3+1]);
      a1[2] = (short)f2bf(pos[(size_t)did*3+2] - pos[(size_t)sid*3+2]);
    }
    f32x4 acc[4];
#pragma unroll
    for(int nt=0;nt<4;nt++)
      acc[nt] = __builtin_amdgcn_mfma_f32_16x16x32_bf16(a1, wp1f[nt], zero, 0,0,0);

    ldsfence();
#pragma unroll
    for(int nt=0;nt<4;nt++)
#pragma unroll
      for(int r=0;r<4;r++)
        lb[(q*4+r)*66 + nt*16 + t] = f2bf(fmaxf(acc[nt][r] + bp1f[nt], 0.f));
    ldsfence();
    bf16x8 at0 = lds_read_chunk(lb32, t*33 + q*4);
    bf16x8 at1 = lds_read_chunk(lb32, t*33 + 16 + q*4);

    // --- P2 -> delta (f32) ---
#pragma unroll
    for(int nt=0;nt<4;nt++){
      acc[nt] = __builtin_amdgcn_mfma_f32_16x16x32_bf16(at0, wp2f[nt][0], zero, 0,0,0);
      acc[nt] = __builtin_amdgcn_mfma_f32_16x16x32_bf16(at1, wp2f[nt][1], acc[nt], 0,0,0);
    }
    float dval[4][4];
#pragma unroll
    for(int nt=0;nt<4;nt++)
#pragma unroll
      for(int r=0;r<4;r++) dval[nt][r] = acc[nt][r] + bp2f[nt];

    ldsfence();
#pragma unroll
    for(int nt=0;nt<4;nt++)
#pragma unroll
      for(int r=0;r<4;r++)
        lf[(q*4+r)*66 + nt*16 + t] = dval[nt][r];
    ldsfence();

    // --- ali = a_dst[did] - a_src[sid] + delta (per-edge dst row) ---
    bf16x8 ali[2];
#pragma unroll
    for(int s=0;s<2;s++){
      float4 d0 = ad4a[(size_t)did*16 + s*8 + q*2], d1 = ad4a[(size_t)did*16 + s*8 + q*2 + 1];
      float4 s0 = as4[(size_t)sid*16 + s*8 + q*2], s1 = as4[(size_t)sid*16 + s*8 + q*2 + 1];
      const float* dl = lf + t*66 + s*32 + q*8;
      ali[s][0]=(short)f2bf(d0.x - s0.x + dl[0]);
      ali[s][1]=(short)f2bf(d0.y - s0.y + dl[1]);
      ali[s][2]=(short)f2bf(d0.z - s0.z + dl[2]);
      ali[s][3]=(short)f2bf(d0.w - s0.w + dl[3]);
      ali[s][4]=(short)f2bf(d1.x - s1.x + dl[4]);
      ali[s][5]=(short)f2bf(d1.y - s1.y + dl[5]);
      ali[s][6]=(short)f2bf(d1.z - s1.z + dl[6]);
      ali[s][7]=(short)f2bf(d1.w - s1.w + dl[7]);
    }

    // --- attn L1 ---
#pragma unroll
    for(int nt=0;nt<4;nt++){
      acc[nt] = __builtin_amdgcn_mfma_f32_16x16x32_bf16(ali[0], wa1f[nt][0], zero, 0,0,0);
      acc[nt] = __builtin_amdgcn_mfma_f32_16x16x32_bf16(ali[1], wa1f[nt][1], acc[nt], 0,0,0);
    }
    ldsfence();
#pragma unroll
    for(int nt=0;nt<4;nt++)
#pragma unroll
      for(int r=0;r<4;r++)
        lb[(q*4+r)*66 + nt*16 + t] = f2bf(fmaxf(acc[nt][r] + ba1f[nt], 0.f));
    ldsfence();
    bf16x8 au0 = lds_read_chunk(lb32, t*33 + q*4);
    bf16x8 au1 = lds_read_chunk(lb32, t*33 + 16 + q*4);

    // --- attn L2 -> w=exp ---
#pragma unroll
    for(int nt=0;nt<4;nt++){
      acc[nt] = __builtin_amdgcn_mfma_f32_16x16x32_bf16(au0, wa2f[nt][0], zero, 0,0,0);
      acc[nt] = __builtin_amdgcn_mfma_f32_16x16x32_bf16(au1, wa2f[nt][1], acc[nt], 0,0,0);
    }
    float wv[4][4];
#pragma unroll
    for(int nt=0;nt<4;nt++)
#pragma unroll
      for(int r=0;r<4;r++){
        bool valid = (tb + q*4 + r) < hi;
        wv[nt][r] = valid ? __expf(fminf(acc[nt][r] + ba2f[nt], 80.f)) : 0.f;
      }

    // --- segmented accumulate over runs of equal dst ---
    int prev = __shfl(did, (t==0)?0:(t-1), 64);
    u64 chg = __ballot((t>0) && (did != prev));
    u32 sm_all;
    int m = 0;
    while(m < 16){
      int d0 = __shfl(did, m, 64);
      u32 same = (u32)(__ballot(did == d0) & 0xFFFFull);
      u32 rest = ~(same >> m);
      int len = __ffs(rest) - 1;          // run length (rest bit0==0, some bit<=16 set)
      int m1 = m + len;
      if(d0 != cur_d){
        flushseg(cur_d, numP, SP, row_start, num, S, lo, hi, q, t);
        cur_d = d0;
      }
#pragma unroll
      for(int r=0;r<4;r++){
        int mm = q*4 + r;
        int sidm = __shfl(sid, mm, 64);
        bool use = (mm >= m) && (mm < m1) && ((tb+mm) < hi);
        if(use){
#pragma unroll
          for(int nt=0;nt<4;nt++){
            float vvalue = vf[(size_t)sidm*64 + nt*16 + t];
            numP[nt] += wv[nt][r] * (vvalue + dval[nt][r]);
            SP[nt]   += wv[nt][r];
          }
        }
      }
      m = m1;
    }
    (void)chg;
  }
  flushseg(cur_d, numP, SP, row_start, num, S, lo, hi, q, t);
}

// ---------- out = relu((num/S) @ Wout + bout), MFMA (validated R5) ----------
__global__ __launch_bounds__(256) void k_out_m(
  const float* __restrict__ num, const float* __restrict__ S,
  const float* __restrict__ Bf, const u16* __restrict__ FB,
  float* __restrict__ out, int N, int ntiles)
{
  int lane = threadIdx.x & 63, warp = threadIdx.x >> 6;
  int t = lane & 15, q = lane >> 4;
  int tile = blockIdx.x*4 + warp;
  if(tile >= ntiles) return;
  int r0 = tile*16;
  int row = r0 + t; if(row >= N) row = N-1;
  const float4* n4 = (const float4*)(num + (size_t)row*64);
  const float4* s4 = (const float4*)(S   + (size_t)row*64);
  bf16x8 af[2];
#pragma unroll
  for(int s=0;s<2;s++){
    float4 n0 = n4[s*8 + q*2], n1 = n4[s*8 + q*2 + 1];
    float4 s0 = s4[s*8 + q*2], s1 = s4[s*8 + q*2 + 1];
    af[s][0]=(short)f2bf(n0.x/(s0.x+1e-16f)); af[s][1]=(short)f2bf(n0.y/(s0.y+1e-16f));
    af[s][2]=(short)f2bf(n0.z/(s0.z+1e-16f)); af[s][3]=(short)f2bf(n0.w/(s0.w+1e-16f));
    af[s][4]=(short)f2bf(n1.x/(s1.x+1e-16f)); af[s][5]=(short)f2bf(n1.y/(s1.y+1e-16f));
    af[s][6]=(short)f2bf(n1.z/(s1.z+1e-16f)); af[s][7]=(short)f2bf(n1.w/(s1.w+1e-16f));
  }
  f32x4 zero = {0.f,0.f,0.f,0.f};
#pragma unroll
  for(int nt=0;nt<4;nt++){
    f32x4 a = __builtin_amdgcn_mfma_f32_16x16x32_bf16(af[0], fb_load(FB, FB_OUT+nt*2+0, lane), zero, 0,0,0);
    a = __builtin_amdgcn_mfma_f32_16x16x32_bf16(af[1], fb_load(FB, FB_OUT+nt*2+1, lane), a, 0,0,0);
    float b = Bf[320 + nt*16 + t];
#pragma unroll
    for(int r=0;r<4;r++){
      int rr = r0 + q*4 + r;
      if(rr < N) out[(size_t)rr*64 + nt*16 + t] = fmaxf(a[r] + b, 0.f);
    }
  }
}

extern "C" void kernel_launch(void* const* d_in, const int* in_sizes, int n_in,
                              void* d_out, int out_size, void* d_ws, size_t ws_size,
                              hipStream_t stream){
  const float* x   =(const float*)d_in[0];
  const float* pos =(const float*)d_in[1];
  const int*   ei  =(const int*)d_in[2];
  const float* Win =(const float*)d_in[3];  const float* bin=(const float*)d_in[4];
  const float* Wlin=(const float*)d_in[5];  const float* Wsrc=(const float*)d_in[6];
  const float* Wdst=(const float*)d_in[7];
  const float* Wp1 =(const float*)d_in[8];  const float* bp1=(const float*)d_in[9];
  const float* Wp2 =(const float*)d_in[10]; const float* bp2=(const float*)d_in[11];
  const float* Wa1 =(const float*)d_in[12]; const float* ba1=(const float*)d_in[13];
  const float* Wa2 =(const float*)d_in[14]; const float* ba2=(const float*)d_in[15];
  const float* Wout=(const float*)d_in[16]; const float* bout=(const float*)d_in[17];
  int N = in_sizes[0]/64;
  int E = in_sizes[2]/2;

  float* Bf   = (float*)d_ws;                       // 384 f32
  u16*   FB   = (u16*)(Bf + NBIAS);                 // NFRAG*64*8 u16
  float* vf   = (float*)(FB + (size_t)NFRAG*64*8);  // [N*64]
  float* asof = vf   + (size_t)N*64;
  float* adof = asof + (size_t)N*64;
  float* S    = adof + (size_t)N*64;
  float* num  = S    + (size_t)N*64;
  int* deg       = (int*)(num + (size_t)N*64);      // [N]
  int* cursor    = deg + N;                         // [N]
  int* row_start = cursor + N;                      // [N+1]
  int* sorted    = row_start + (N+1);               // [E]
  int* sortedd   = sorted + E;                      // [E]

  int ntiles = (N+15)/16;
  int ntile_e = (E+15)/16;
  int total_waves = 4096;                           // 1024 blocks x 4 waves
  int tpw = (ntile_e + total_waves - 1) / total_waves;

  hipMemsetAsync(deg, 0, (size_t)2*N*sizeof(int), stream);          // deg + cursor
  hipMemsetAsync(S, 0, (size_t)N*64*2*sizeof(float), stream);       // S + num
  k_prep<<<dim3(19), dim3(256), 0, stream>>>(Win,Wlin,Wsrc,Wdst,Wp1,Wp2,Wa1,Wa2,Wout,
                                             bin,bp1,bp2,ba1,ba2,bout, Bf, FB);
  k_node_m<<<dim3((ntiles+3)/4), dim3(256), 0, stream>>>(x, Bf, FB, vf, asof, adof, N, ntiles);
  k_hist<<<dim3((E+255)/256), dim3(256), 0, stream>>>(ei, deg, E);
  k_scan<<<dim3(1), dim3(1024), 0, stream>>>(deg, row_start, N);
  k_scatter<<<dim3((E+255)/256), dim3(256), 0, stream>>>(ei, row_start, cursor, sorted, sortedd, E);
  k_edge_p<<<dim3(1024), dim3(256), 0, stream>>>(row_start, sorted, sortedd, pos, Bf, FB,
                                                 vf, asof, adof, S, num, E, ntile_e, tpw);
  k_out_m<<<dim3((ntiles+3)/4), dim3(256), 0, stream>>>(num, S, Bf, FB, (float*)d_out, N, ntiles);
}

// Round 7
// 443.027 us; speedup vs baseline: 12.9828x; 1.0234x over previous
//
#include <hip/hip_runtime.h>

typedef unsigned short u16;
typedef unsigned int   u32;
typedef unsigned long long u64;
typedef __attribute__((ext_vector_type(8))) short bf16x8;
typedef __attribute__((ext_vector_type(4))) float f32x4;

#define DEV static __device__ __forceinline__

DEV u16 f2bf(float f){ union{float f; u32 i;} v; v.f=f; u32 u=v.i;
                       return (u16)((u + 0x7FFFu + ((u>>16)&1u))>>16); }
DEV void ldsfence(){ asm volatile("s_waitcnt lgkmcnt(0)" ::: "memory"); }

// ---- bias slab (f32): bin,bp1,bp2,ba1,ba2,bout ----
#define NBIAS 384
// ---- fragment buffer FB: [frag][lane][8] u16 ----
#define FB_P1 0
#define FB_P2 4
#define FB_A1 12
#define FB_A2 20
#define FB_IN 28
#define FB_LIN 36
#define FB_SRC 44
#define FB_DST 52
#define FB_OUT 60
#define NFRAG 68

DEV bf16x8 fb_load(const u16* __restrict__ FB, int frag, int lane){
  union{ uint4 u; bf16x8 v; } w;
  w.u = *(const uint4*)(FB + ((size_t)(frag*64+lane))*8);
  return w.v;
}
DEV bf16x8 lds_read_chunk(const u32* l32, int dw){
  union{ u32 d[4]; bf16x8 v; } u;
#pragma unroll
  for(int p=0;p<4;p++) u.d[p] = l32[dw+p];
  return u.v;
}

// ---------- prep: bias slab + per-lane fragment buffer ----------
__global__ __launch_bounds__(256) void k_prep(
  const float* __restrict__ Win, const float* __restrict__ Wlin,
  const float* __restrict__ Wsrc, const float* __restrict__ Wdst,
  const float* __restrict__ Wp1, const float* __restrict__ Wp2,
  const float* __restrict__ Wa1, const float* __restrict__ Wa2,
  const float* __restrict__ Wout,
  const float* __restrict__ bin, const float* __restrict__ bp1, const float* __restrict__ bp2,
  const float* __restrict__ ba1, const float* __restrict__ ba2, const float* __restrict__ bout,
  float* __restrict__ Bf, u16* __restrict__ FB)
{
  int idx = blockIdx.x*256 + threadIdx.x;
  if(idx < NBIAS){
    int which = idx >> 6, c = idx & 63;
    const float* b;
    switch(which){ case 0:b=bin;break; case 1:b=bp1;break; case 2:b=bp2;break;
                   case 3:b=ba1;break; case 4:b=ba2;break; default:b=bout;break; }
    Bf[idx] = b[c];
  } else if(idx < NBIAS + NFRAG*64){
    int j = idx - NBIAS;
    int frag = j >> 6, lane = j & 63;
    int t = lane & 15, q = lane >> 4;
    const float* src; int K = 64, nt, s;
    if(frag < 4){ src = Wp1; K = 3; nt = frag; s = 0; }
    else if(frag < 12){ int g=frag-4;  src=Wp2;  nt=g>>1; s=g&1; }
    else if(frag < 20){ int g=frag-12; src=Wa1;  nt=g>>1; s=g&1; }
    else if(frag < 28){ int g=frag-20; src=Wa2;  nt=g>>1; s=g&1; }
    else if(frag < 36){ int g=frag-28; src=Win;  nt=g>>1; s=g&1; }
    else if(frag < 44){ int g=frag-36; src=Wlin; nt=g>>1; s=g&1; }
    else if(frag < 52){ int g=frag-44; src=Wsrc; nt=g>>1; s=g&1; }
    else if(frag < 60){ int g=frag-52; src=Wdst; nt=g>>1; s=g&1; }
    else              { int g=frag-60; src=Wout; nt=g>>1; s=g&1; }
    u16* dst = FB + ((size_t)(frag*64+lane))*8;
#pragma unroll
    for(int jj=0;jj<8;jj++){
      int k = s*32 + q*8 + jj;
      dst[jj] = (k<K) ? f2bf(src[k*64 + nt*16 + t]) : (u16)0;
    }
  }
}

// ---------- node side, MFMA (validated R5) ----------
__global__ __launch_bounds__(256) void k_node_m(
  const float* __restrict__ x, const float* __restrict__ Bf, const u16* __restrict__ FB,
  float* __restrict__ vf, float* __restrict__ asof, float* __restrict__ adof,
  int N, int ntiles)
{
  __shared__ u16 sc16[4][16*66];
  int lane = threadIdx.x & 63, warp = threadIdx.x >> 6;
  int t = lane & 15, q = lane >> 4;
  int tile = blockIdx.x*4 + warp;
  if(tile >= ntiles) return;
  u16* lb = sc16[warp]; u32* lb32 = (u32*)lb;
  int r0 = tile*16;
  int row = r0 + t; if(row >= N) row = N-1;

  const float4* x4 = (const float4*)(x + (size_t)row*64);
  bf16x8 xa[2];
#pragma unroll
  for(int s=0;s<2;s++){
    float4 u0 = x4[s*8 + q*2], u1 = x4[s*8 + q*2 + 1];
    xa[s][0]=(short)f2bf(u0.x); xa[s][1]=(short)f2bf(u0.y);
    xa[s][2]=(short)f2bf(u0.z); xa[s][3]=(short)f2bf(u0.w);
    xa[s][4]=(short)f2bf(u1.x); xa[s][5]=(short)f2bf(u1.y);
    xa[s][6]=(short)f2bf(u1.z); xa[s][7]=(short)f2bf(u1.w);
  }
  f32x4 zero = {0.f,0.f,0.f,0.f};
  f32x4 acc[4];
#pragma unroll
  for(int nt=0;nt<4;nt++){
    acc[nt] = __builtin_amdgcn_mfma_f32_16x16x32_bf16(xa[0], fb_load(FB, FB_IN+nt*2+0, lane), zero, 0,0,0);
    acc[nt] = __builtin_amdgcn_mfma_f32_16x16x32_bf16(xa[1], fb_load(FB, FB_IN+nt*2+1, lane), acc[nt], 0,0,0);
  }
#pragma unroll
  for(int nt=0;nt<4;nt++)
#pragma unroll
    for(int r=0;r<4;r++)
      lb[(q*4+r)*66 + nt*16 + t] = f2bf(fmaxf(acc[nt][r] + Bf[nt*16+t], 0.f));
  ldsfence();
  bf16x8 h0 = lds_read_chunk(lb32, t*33 + q*4);
  bf16x8 h1 = lds_read_chunk(lb32, t*33 + 16 + q*4);

  const int fb0[3] = {FB_LIN, FB_SRC, FB_DST};
  float* Os[3] = {vf, asof, adof};
#pragma unroll
  for(int mtx=0; mtx<3; mtx++){
    float* O = Os[mtx];
#pragma unroll
    for(int nt=0;nt<4;nt++){
      f32x4 a = __builtin_amdgcn_mfma_f32_16x16x32_bf16(h0, fb_load(FB, fb0[mtx]+nt*2+0, lane), zero, 0,0,0);
      a = __builtin_amdgcn_mfma_f32_16x16x32_bf16(h1, fb_load(FB, fb0[mtx]+nt*2+1, lane), a, 0,0,0);
#pragma unroll
      for(int r=0;r<4;r++){
        int rr = r0 + q*4 + r;
        if(rr < N) O[(size_t)rr*64 + nt*16 + t] = a[r];
      }
    }
  }
}

// ---------- CSR build ----------
__global__ __launch_bounds__(256) void k_hist(const int* __restrict__ ei, int* __restrict__ deg, int E){
  int e = blockIdx.x*256 + threadIdx.x;
  if(e < E) atomicAdd(&deg[ei[(size_t)E + e]], 1);
}

__global__ __launch_bounds__(1024) void k_scan(const int* __restrict__ deg,
                                               int* __restrict__ row_start, int N){
  __shared__ int buf[1024];
  int tid = threadIdx.x;
  int M = (N + 1023) >> 10;
  int lo = tid*M, hi = lo+M; if(hi>N) hi=N; if(lo>N) lo=N;
  int s = 0;
  for(int j=lo;j<hi;j++) s += deg[j];
  buf[tid] = s; __syncthreads();
#pragma unroll
  for(int off=1; off<1024; off<<=1){
    int u = (tid>=off) ? buf[tid-off] : 0;
    __syncthreads();
    buf[tid] += u;
    __syncthreads();
  }
  int b = buf[tid] - s;
  for(int j=lo;j<hi;j++){ row_start[j] = b; b += deg[j]; }
  if(tid==1023) row_start[N] = buf[1023];
}

__global__ __launch_bounds__(256) void k_scatter(const int* __restrict__ ei,
    const int* __restrict__ row_start, int* __restrict__ cursor,
    int* __restrict__ sorted_src, int* __restrict__ sorted_dst, int E){
  int e = blockIdx.x*256 + threadIdx.x;
  if(e >= E) return;
  int d = ei[(size_t)E + e];
  int p = atomicAdd(&cursor[d], 1);
  int pos = row_start[d] + p;
  sorted_src[pos] = ei[e];
  sorted_dst[pos] = d;
}

// ---------- segment flush ----------
DEV void flushseg(int d, float* numP, float* SP, const int* __restrict__ row_start,
                  float* __restrict__ num, float* __restrict__ S,
                  int lo, int hi, int q, int t){
  if(d < 0) return;
#pragma unroll
  for(int nt=0;nt<4;nt++){
    numP[nt] += __shfl_xor(numP[nt], 16, 64);
    numP[nt] += __shfl_xor(numP[nt], 32, 64);
    SP[nt]   += __shfl_xor(SP[nt],   16, 64);
    SP[nt]   += __shfl_xor(SP[nt],   32, 64);
  }
  bool partial = (row_start[d] < lo) || (row_start[d+1] > hi);
  if(q==0){
#pragma unroll
    for(int nt=0;nt<4;nt++){
      size_t off = (size_t)d*64 + nt*16 + t;
      if(partial){ atomicAdd(&num[off], numP[nt]); atomicAdd(&S[off], SP[nt]); }
      else       { num[off] = numP[nt]; S[off] = SP[nt]; }
    }
  }
#pragma unroll
  for(int nt=0;nt<4;nt++){ numP[nt]=0.f; SP[nt]=0.f; }
}

// ---------- segmented accumulate for one 16-edge tile ----------
DEV void agg_tile(int tbase, int hi_w, int lo_w, int sid, int did,
                  const float wv[4][4], const float pd[4][4],
                  int& cur_d, float* numP, float* SP,
                  const int* __restrict__ row_start,
                  float* __restrict__ num, float* __restrict__ S, int q, int t){
  int m = 0;
  while(m < 16){
    int d0 = __shfl(did, m, 64);
    u32 same = (u32)(__ballot(did == d0) & 0xFFFFull);
    u32 rest = ~(same >> m);
    int len = __ffs(rest) - 1;
    int m1 = m + len;
    if(d0 != cur_d){
      flushseg(cur_d, numP, SP, row_start, num, S, lo_w, hi_w, q, t);
      cur_d = d0;
    }
#pragma unroll
    for(int r=0;r<4;r++){
      int mm = q*4 + r;
      bool use = (mm >= m) && (mm < m1) && ((tbase+mm) < hi_w);
      if(use){
#pragma unroll
        for(int nt=0;nt<4;nt++){
          numP[nt] += wv[nt][r] * pd[r][nt];
          SP[nt]   += wv[nt][r];
        }
      }
    }
    m = m1;
  }
}

// ---------- packed edge pipeline: 2 interleaved 16-edge chains per wave ----------
__global__ __launch_bounds__(256,2) void k_edge_p2(
  const int* __restrict__ row_start,
  const int* __restrict__ sorted_src, const int* __restrict__ sorted_dst,
  const float* __restrict__ pos, const float* __restrict__ Bf, const u16* __restrict__ FB,
  const float* __restrict__ vf, const float* __restrict__ asof, const float* __restrict__ adof,
  float* __restrict__ S, float* __restrict__ num, int E, int nsuper, int spw)
{
  __shared__ u16   sc16[4][32*66];   // rows 0-15 tile A, 16-31 tile B
  __shared__ float scf [4][32*66];
  int lane = threadIdx.x & 63, warp = threadIdx.x >> 6;
  int t = lane & 15, q = lane >> 4;
  int wid = blockIdx.x*4 + warp;
  int s0 = wid*spw, s1 = s0 + spw;
  if(s0 >= nsuper) return;
  if(s1 > nsuper) s1 = nsuper;
  int lo = s0*32, hi = s1*32; if(hi > E) hi = E;
  u16* lb = sc16[warp]; u32* lb32 = (u32*)lb;
  float* lf = scf[warp];

  // resident: Wp1 frags + biases only
  bf16x8 wp1f[4];
#pragma unroll
  for(int nt=0;nt<4;nt++) wp1f[nt] = fb_load(FB, FB_P1+nt, lane);
  float bp1f[4], bp2f[4], ba1f[4], ba2f[4];
#pragma unroll
  for(int nt=0;nt<4;nt++){
    bp1f[nt]=Bf[ 64+nt*16+t]; bp2f[nt]=Bf[128+nt*16+t];
    ba1f[nt]=Bf[192+nt*16+t]; ba2f[nt]=Bf[256+nt*16+t];
  }
  const float4* as4 = (const float4*)asof;
  const float4* ad4 = (const float4*)adof;
  f32x4 zero = {0.f,0.f,0.f,0.f};
  float numP[4] = {0,0,0,0}, SP[4] = {0,0,0,0};
  int cur_d = -1;

  for(int tb = lo; tb < hi; tb += 32){
    bool hasB = (tb+16) < hi;
    int ecA = tb + t;        if(ecA >= hi) ecA = hi-1;
    int ecB = tb + 16 + t;   if(ecB >= hi) ecB = hi-1;
    int sidA = sorted_src[ecA], didA = sorted_dst[ecA];
    int sidB = sorted_src[ecB], didB = sorted_dst[ecB];

    // --- P1 (both chains) ---
    bf16x8 a1A, a1B;
#pragma unroll
    for(int j=0;j<8;j++){ a1A[j]=0; a1B[j]=0; }
    if(q==0){
      a1A[0] = (short)f2bf(pos[(size_t)didA*3+0] - pos[(size_t)sidA*3+0]);
      a1A[1] = (short)f2bf(pos[(size_t)didA*3+1] - pos[(size_t)sidA*3+1]);
      a1A[2] = (short)f2bf(pos[(size_t)didA*3+2] - pos[(size_t)sidA*3+2]);
      a1B[0] = (short)f2bf(pos[(size_t)didB*3+0] - pos[(size_t)sidB*3+0]);
      a1B[1] = (short)f2bf(pos[(size_t)didB*3+1] - pos[(size_t)sidB*3+1]);
      a1B[2] = (short)f2bf(pos[(size_t)didB*3+2] - pos[(size_t)sidB*3+2]);
    }
    f32x4 accA[4], accB[4];
#pragma unroll
    for(int nt=0;nt<4;nt++){
      accA[nt] = __builtin_amdgcn_mfma_f32_16x16x32_bf16(a1A, wp1f[nt], zero, 0,0,0);
      accB[nt] = __builtin_amdgcn_mfma_f32_16x16x32_bf16(a1B, wp1f[nt], zero, 0,0,0);
    }

    ldsfence();                     // WAR vs prev supertile's au reads
#pragma unroll
    for(int nt=0;nt<4;nt++)
#pragma unroll
      for(int r=0;r<4;r++){
        lb[(     q*4+r)*66 + nt*16 + t] = f2bf(fmaxf(accA[nt][r] + bp1f[nt], 0.f));
        lb[(16 + q*4+r)*66 + nt*16 + t] = f2bf(fmaxf(accB[nt][r] + bp1f[nt], 0.f));
      }
    ldsfence();
    bf16x8 atA0 = lds_read_chunk(lb32, (t   )*33 + q*4);
    bf16x8 atA1 = lds_read_chunk(lb32, (t   )*33 + 16 + q*4);
    bf16x8 atB0 = lds_read_chunk(lb32, (t+16)*33 + q*4);
    bf16x8 atB1 = lds_read_chunk(lb32, (t+16)*33 + 16 + q*4);

    // --- P2 -> delta (weights from FB, shared A/B) ---
#pragma unroll
    for(int nt=0;nt<4;nt++){
      bf16x8 w0 = fb_load(FB, FB_P2+nt*2+0, lane);
      bf16x8 w1 = fb_load(FB, FB_P2+nt*2+1, lane);
      accA[nt] = __builtin_amdgcn_mfma_f32_16x16x32_bf16(atA0, w0, zero, 0,0,0);
      accA[nt] = __builtin_amdgcn_mfma_f32_16x16x32_bf16(atA1, w1, accA[nt], 0,0,0);
      accB[nt] = __builtin_amdgcn_mfma_f32_16x16x32_bf16(atB0, w0, zero, 0,0,0);
      accB[nt] = __builtin_amdgcn_mfma_f32_16x16x32_bf16(atB1, w1, accB[nt], 0,0,0);
    }
    float dvalA[4][4], dvalB[4][4];
#pragma unroll
    for(int nt=0;nt<4;nt++)
#pragma unroll
      for(int r=0;r<4;r++){
        dvalA[nt][r] = accA[nt][r] + bp2f[nt];
        dvalB[nt][r] = accB[nt][r] + bp2f[nt];
      }

    ldsfence();                     // WAR vs prev supertile's lf reads
#pragma unroll
    for(int nt=0;nt<4;nt++)
#pragma unroll
      for(int r=0;r<4;r++){
        lf[(     q*4+r)*66 + nt*16 + t] = dvalA[nt][r];
        lf[(16 + q*4+r)*66 + nt*16 + t] = dvalB[nt][r];
      }
    ldsfence();

    // --- ali = a_dst - a_src + delta (both chains) ---
    bf16x8 aliA[2], aliB[2];
#pragma unroll
    for(int s=0;s<2;s++){
      float4 dA0 = ad4[(size_t)didA*16 + s*8 + q*2], dA1 = ad4[(size_t)didA*16 + s*8 + q*2 + 1];
      float4 sA0 = as4[(size_t)sidA*16 + s*8 + q*2], sA1 = as4[(size_t)sidA*16 + s*8 + q*2 + 1];
      float4 dB0 = ad4[(size_t)didB*16 + s*8 + q*2], dB1 = ad4[(size_t)didB*16 + s*8 + q*2 + 1];
      float4 sB0 = as4[(size_t)sidB*16 + s*8 + q*2], sB1 = as4[(size_t)sidB*16 + s*8 + q*2 + 1];
      const float* dlA = lf + (t   )*66 + s*32 + q*8;
      const float* dlB = lf + (t+16)*66 + s*32 + q*8;
      aliA[s][0]=(short)f2bf(dA0.x - sA0.x + dlA[0]);
      aliA[s][1]=(short)f2bf(dA0.y - sA0.y + dlA[1]);
      aliA[s][2]=(short)f2bf(dA0.z - sA0.z + dlA[2]);
      aliA[s][3]=(short)f2bf(dA0.w - sA0.w + dlA[3]);
      aliA[s][4]=(short)f2bf(dA1.x - sA1.x + dlA[4]);
      aliA[s][5]=(short)f2bf(dA1.y - sA1.y + dlA[5]);
      aliA[s][6]=(short)f2bf(dA1.z - sA1.z + dlA[6]);
      aliA[s][7]=(short)f2bf(dA1.w - sA1.w + dlA[7]);
      aliB[s][0]=(short)f2bf(dB0.x - sB0.x + dlB[0]);
      aliB[s][1]=(short)f2bf(dB0.y - sB0.y + dlB[1]);
      aliB[s][2]=(short)f2bf(dB0.z - sB0.z + dlB[2]);
      aliB[s][3]=(short)f2bf(dB0.w - sB0.w + dlB[3]);
      aliB[s][4]=(short)f2bf(dB1.x - sB1.x + dlB[4]);
      aliB[s][5]=(short)f2bf(dB1.y - sB1.y + dlB[5]);
      aliB[s][6]=(short)f2bf(dB1.z - sB1.z + dlB[6]);
      aliB[s][7]=(short)f2bf(dB1.w - sB1.w + dlB[7]);
    }

    // --- attn L1 ---
#pragma unroll
    for(int nt=0;nt<4;nt++){
      bf16x8 w0 = fb_load(FB, FB_A1+nt*2+0, lane);
      bf16x8 w1 = fb_load(FB, FB_A1+nt*2+1, lane);
      accA[nt] = __builtin_amdgcn_mfma_f32_16x16x32_bf16(aliA[0], w0, zero, 0,0,0);
      accA[nt] = __builtin_amdgcn_mfma_f32_16x16x32_bf16(aliA[1], w1, accA[nt], 0,0,0);
      accB[nt] = __builtin_amdgcn_mfma_f32_16x16x32_bf16(aliB[0], w0, zero, 0,0,0);
      accB[nt] = __builtin_amdgcn_mfma_f32_16x16x32_bf16(aliB[1], w1, accB[nt], 0,0,0);
    }
    ldsfence();                     // WAR vs at reads
#pragma unroll
    for(int nt=0;nt<4;nt++)
#pragma unroll
      for(int r=0;r<4;r++){
        lb[(     q*4+r)*66 + nt*16 + t] = f2bf(fmaxf(accA[nt][r] + ba1f[nt], 0.f));
        lb[(16 + q*4+r)*66 + nt*16 + t] = f2bf(fmaxf(accB[nt][r] + ba1f[nt], 0.f));
      }
    ldsfence();

    // batched v-gathers (overlap with au reads + L2 mfma)
    float vrawA[4][4], vrawB[4][4];
#pragma unroll
    for(int r=0;r<4;r++){
      int mm = q*4 + r;
      int sA = __shfl(sidA, mm, 64);
      int sB = __shfl(sidB, mm, 64);
#pragma unroll
      for(int nt=0;nt<4;nt++){
        vrawA[r][nt] = vf[(size_t)sA*64 + nt*16 + t];
        vrawB[r][nt] = vf[(size_t)sB*64 + nt*16 + t];
      }
    }

    bf16x8 auA0 = lds_read_chunk(lb32, (t   )*33 + q*4);
    bf16x8 auA1 = lds_read_chunk(lb32, (t   )*33 + 16 + q*4);
    bf16x8 auB0 = lds_read_chunk(lb32, (t+16)*33 + q*4);
    bf16x8 auB1 = lds_read_chunk(lb32, (t+16)*33 + 16 + q*4);

    // --- attn L2 -> w=exp ---
#pragma unroll
    for(int nt=0;nt<4;nt++){
      bf16x8 w0 = fb_load(FB, FB_A2+nt*2+0, lane);
      bf16x8 w1 = fb_load(FB, FB_A2+nt*2+1, lane);
      accA[nt] = __builtin_amdgcn_mfma_f32_16x16x32_bf16(auA0, w0, zero, 0,0,0);
      accA[nt] = __builtin_amdgcn_mfma_f32_16x16x32_bf16(auA1, w1, accA[nt], 0,0,0);
      accB[nt] = __builtin_amdgcn_mfma_f32_16x16x32_bf16(auB0, w0, zero, 0,0,0);
      accB[nt] = __builtin_amdgcn_mfma_f32_16x16x32_bf16(auB1, w1, accB[nt], 0,0,0);
    }
    float wvA[4][4], wvB[4][4], pdA[4][4], pdB[4][4];
#pragma unroll
    for(int nt=0;nt<4;nt++)
#pragma unroll
      for(int r=0;r<4;r++){
        wvA[nt][r] = ((tb + q*4 + r) < hi)      ? __expf(fminf(accA[nt][r] + ba2f[nt], 80.f)) : 0.f;
        wvB[nt][r] = ((tb + 16 + q*4 + r) < hi) ? __expf(fminf(accB[nt][r] + ba2f[nt], 80.f)) : 0.f;
      }
#pragma unroll
    for(int r=0;r<4;r++)
#pragma unroll
      for(int nt=0;nt<4;nt++){
        pdA[r][nt] = vrawA[r][nt] + dvalA[nt][r];
        pdB[r][nt] = vrawB[r][nt] + dvalB[nt][r];
      }

    // --- segmented accumulate: tile A then tile B ---
    agg_tile(tb,      hi, lo, sidA, didA, wvA, pdA, cur_d, numP, SP, row_start, num, S, q, t);
    if(hasB)
      agg_tile(tb+16, hi, lo, sidB, didB, wvB, pdB, cur_d, numP, SP, row_start, num, S, q, t);
  }
  flushseg(cur_d, numP, SP, row_start, num, S, lo, hi, q, t);
}

// ---------- out = relu((num/S) @ Wout + bout), MFMA (validated R5) ----------
__global__ __launch_bounds__(256) void k_out_m(
  const float* __restrict__ num, const float* __restrict__ S,
  const float* __restrict__ Bf, const u16* __restrict__ FB,
  float* __restrict__ out, int N, int ntiles)
{
  int lane = threadIdx.x & 63, warp = threadIdx.x >> 6;
  int t = lane & 15, q = lane >> 4;
  int tile = blockIdx.x*4 + warp;
  if(tile >= ntiles) return;
  int r0 = tile*16;
  int row = r0 + t; if(row >= N) row = N-1;
  const float4* n4 = (const float4*)(num + (size_t)row*64);
  const float4* s4 = (const float4*)(S   + (size_t)row*64);
  bf16x8 af[2];
#pragma unroll
  for(int s=0;s<2;s++){
    float4 n0 = n4[s*8 + q*2], n1 = n4[s*8 + q*2 + 1];
    float4 s0 = s4[s*8 + q*2], s1 = s4[s*8 + q*2 + 1];
    af[s][0]=(short)f2bf(n0.x/(s0.x+1e-16f)); af[s][1]=(short)f2bf(n0.y/(s0.y+1e-16f));
    af[s][2]=(short)f2bf(n0.z/(s0.z+1e-16f)); af[s][3]=(short)f2bf(n0.w/(s0.w+1e-16f));
    af[s][4]=(short)f2bf(n1.x/(s1.x+1e-16f)); af[s][5]=(short)f2bf(n1.y/(s1.y+1e-16f));
    af[s][6]=(short)f2bf(n1.z/(s1.z+1e-16f)); af[s][7]=(short)f2bf(n1.w/(s1.w+1e-16f));
  }
  f32x4 zero = {0.f,0.f,0.f,0.f};
#pragma unroll
  for(int nt=0;nt<4;nt++){
    f32x4 a = __builtin_amdgcn_mfma_f32_16x16x32_bf16(af[0], fb_load(FB, FB_OUT+nt*2+0, lane), zero, 0,0,0);
    a = __builtin_amdgcn_mfma_f32_16x16x32_bf16(af[1], fb_load(FB, FB_OUT+nt*2+1, lane), a, 0,0,0);
    float b = Bf[320 + nt*16 + t];
#pragma unroll
    for(int r=0;r<4;r++){
      int rr = r0 + q*4 + r;
      if(rr < N) out[(size_t)rr*64 + nt*16 + t] = fmaxf(a[r] + b, 0.f);
    }
  }
}

extern "C" void kernel_launch(void* const* d_in, const int* in_sizes, int n_in,
                              void* d_out, int out_size, void* d_ws, size_t ws_size,
                              hipStream_t stream){
  const float* x   =(const float*)d_in[0];
  const float* pos =(const float*)d_in[1];
  const int*   ei  =(const int*)d_in[2];
  const float* Win =(const float*)d_in[3];  const float* bin=(const float*)d_in[4];
  const float* Wlin=(const float*)d_in[5];  const float* Wsrc=(const float*)d_in[6];
  const float* Wdst=(const float*)d_in[7];
  const float* Wp1 =(const float*)d_in[8];  const float* bp1=(const float*)d_in[9];
  const float* Wp2 =(const float*)d_in[10]; const float* bp2=(const float*)d_in[11];
  const float* Wa1 =(const float*)d_in[12]; const float* ba1=(const float*)d_in[13];
  const float* Wa2 =(const float*)d_in[14]; const float* ba2=(const float*)d_in[15];
  const float* Wout=(const float*)d_in[16]; const float* bout=(const float*)d_in[17];
  int N = in_sizes[0]/64;
  int E = in_sizes[2]/2;

  float* Bf   = (float*)d_ws;
  u16*   FB   = (u16*)(Bf + NBIAS);
  float* vf   = (float*)(FB + (size_t)NFRAG*64*8);
  float* asof = vf   + (size_t)N*64;
  float* adof = asof + (size_t)N*64;
  float* S    = adof + (size_t)N*64;
  float* num  = S    + (size_t)N*64;
  int* deg       = (int*)(num + (size_t)N*64);
  int* cursor    = deg + N;
  int* row_start = cursor + N;
  int* sorted    = row_start + (N+1);
  int* sortedd   = sorted + E;

  int ntiles = (N+15)/16;
  int nsuper = (E+31)/32;
  int total_waves = 4096;
  int spw = (nsuper + total_waves - 1) / total_waves;
  int eblocks = (nsuper + 4*spw - 1) / (4*spw);

  hipMemsetAsync(deg, 0, (size_t)2*N*sizeof(int), stream);
  hipMemsetAsync(S, 0, (size_t)N*64*2*sizeof(float), stream);
  k_prep<<<dim3(19), dim3(256), 0, stream>>>(Win,Wlin,Wsrc,Wdst,Wp1,Wp2,Wa1,Wa2,Wout,
                                             bin,bp1,bp2,ba1,ba2,bout, Bf, FB);
  k_node_m<<<dim3((ntiles+3)/4), dim3(256), 0, stream>>>(x, Bf, FB, vf, asof, adof, N, ntiles);
  k_hist<<<dim3((E+255)/256), dim3(256), 0, stream>>>(ei, deg, E);
  k_scan<<<dim3(1), dim3(1024), 0, stream>>>(deg, row_start, N);
  k_scatter<<<dim3((E+255)/256), dim3(256), 0, stream>>>(ei, row_start, cursor, sorted, sortedd, E);
  k_edge_p2<<<dim3(eblocks), dim3(256), 0, stream>>>(row_start, sorted, sortedd, pos, Bf, FB,
                                                     vf, asof, adof, S, num, E, nsuper, spw);
  k_out_m<<<dim3((ntiles+3)/4), dim3(256), 0, stream>>>(num, S, Bf, FB, (float*)d_out, N, ntiles);
}